// Round 1
// baseline (893.177 us; speedup 1.0000x reference)
//
#include <hip/hip_runtime.h>
#include <stdint.h>
#include <math.h>

#define DEVI __device__ __forceinline__
typedef unsigned short ushort_t;
typedef __attribute__((ext_vector_type(8))) __bf16 bf16x8;
typedef __attribute__((ext_vector_type(4))) float f32x4;

// ---------- scalar bf16 helpers (RNE, matches HW/harness encoding) ----------
DEVI float bf2f(ushort_t b){ union{uint32_t u; float f;} c; c.u = ((uint32_t)b) << 16; return c.f; }
DEVI ushort_t f2bf(float f){ union{float f; uint32_t u;} c; c.f = f; uint32_t u = c.u;
                             u += 0x7fffu + ((u >> 16) & 1u); return (ushort_t)(u >> 16); }

// ---------- async global->LDS (16B per lane, dest = wave-uniform base + lane*16) ----------
DEVI void async16(const ushort_t* g, ushort_t* l){
  __builtin_amdgcn_global_load_lds((const __attribute__((address_space(1))) void*)g,
                                   (__attribute__((address_space(3))) void*)l, 16, 0, 0);
}

// ---------- problem constants ----------
#define BB 32768
#define INDIM 256
#define LATENT 128
#define HID 1024
#define KCODES 1024

// =====================================================================
// dtype sniffer: if inputs are fp32, every other bf16-half of `action`
// is fp32-mantissa garbage with a uniform-random exponent.
// flag = 1 -> buffers are bf16 ; flag = 0 -> fp32
// =====================================================================
__global__ void k_sniff(const ushort_t* __restrict__ act, int* flag, float* loss_acc){
  if (threadIdx.x == 0){
    int bad = 0;
    for (int i = 0; i < 256; i++){
      float v = bf2f(act[i]);
      float a = fabsf(v);
      if (!(a <= 16.0f) || (a > 0.0f && a < 9.5e-7f)) bad++;
    }
    flag[0] = (bad >= 8) ? 0 : 1;
    loss_acc[0] = 0.0f;
  }
}

// convert (no transpose) to bf16 bits
__global__ void k_cvt(const void* __restrict__ src, ushort_t* __restrict__ dst, int n,
                      const int* __restrict__ flagp){
  int f = *flagp;
  for (int i = blockIdx.x * blockDim.x + threadIdx.x; i < n; i += gridDim.x * blockDim.x){
    dst[i] = f ? ((const ushort_t*)src)[i] : f2bf(((const float*)src)[i]);
  }
}

// convert + transpose: src[R][C] -> dst[C][R] (bf16). grid(C/32, R/32), block 256
__global__ void k_tcvt(const void* __restrict__ src, ushort_t* __restrict__ dst, int R, int C,
                       const int* __restrict__ flagp){
  __shared__ ushort_t tile[32][33];
  int f = *flagp;
  int tx = threadIdx.x & 31, ty = threadIdx.x >> 5;
  int c = blockIdx.x * 32 + tx;
  #pragma unroll
  for (int ii = 0; ii < 4; ii++){
    int r = blockIdx.y * 32 + ty + ii * 8;
    long idx = (long)r * C + c;
    tile[ty + ii * 8][tx] = f ? ((const ushort_t*)src)[idx] : f2bf(((const float*)src)[idx]);
  }
  __syncthreads();
  #pragma unroll
  for (int ii = 0; ii < 4; ii++){
    int cc = blockIdx.x * 32 + ty + ii * 8;
    dst[(long)cc * R + blockIdx.y * 32 + tx] = tile[tx][ty + ii * 8];
  }
}

// all 6 biases -> fp32, 1024-float slots. grid 24 x 256
__global__ void k_bias(const void* s0, const void* s1, const void* s2,
                       const void* s3, const void* s4, const void* s5,
                       float* __restrict__ d, const int* __restrict__ flagp){
  int f = *flagp;
  int i = blockIdx.x * blockDim.x + threadIdx.x;
  int seg = i >> 10, off = i & 1023;
  const void* sp; int n;
  switch (seg){
    case 0: sp = s0; n = 1024; break;
    case 1: sp = s1; n = 1024; break;
    case 2: sp = s2; n = 128;  break;
    case 3: sp = s3; n = 1024; break;
    case 4: sp = s4; n = 1024; break;
    default: sp = s5; n = 256; break;
  }
  if (off < n)
    d[seg * 1024 + off] = f ? bf2f(((const ushort_t*)sp)[off]) : ((const float*)sp)[off];
}

// ||e_c||^2 from bf16 codebook. grid 4 x 256
__global__ void k_enorm(const ushort_t* __restrict__ embb, float* __restrict__ enorm){
  int c = blockIdx.x * blockDim.x + threadIdx.x;
  if (c < KCODES){
    float s = 0.f;
    for (int d = 0; d < LATENT; d++){ float v = bf2f(embb[c * LATENT + d]); s += v * v; }
    enorm[c] = s;
  }
}

// =====================================================================
// generic MFMA GEMM: C[M,N] = A[M,K] @ Bt[N,K]^T (+bias) (+tanh)
// 128x128 tile / workgroup, 4 waves in 2x2, each 4x4 of 16x16x32 MFMAs.
// MODE 0: out = bf16 activation buffer (TANH optional)
// MODE 1: z: fp32 buf + bf16 buf + d_out (flag dtype)
// MODE 2: recon: d_out only (flag dtype)
// MODE 3: VQ scores: acc - 0.5*enorm[col], per-row argmax -> candidates
// =====================================================================
template<int MODE, int TANH>
__global__ __launch_bounds__(256)
void k_gemm(const ushort_t* __restrict__ A, const ushort_t* __restrict__ Bt,
            const float* __restrict__ bias, int M, int N, int K,
            ushort_t* __restrict__ outb, float* __restrict__ outf,
            void* __restrict__ dout, long dout_off,
            const float* __restrict__ enorm,
            float* __restrict__ cand_v, int* __restrict__ cand_i,
            const int* __restrict__ flagp)
{
  __shared__ __align__(16) ushort_t As[128 * 32];
  __shared__ __align__(16) ushort_t Bs[128 * 32];
  const int tid = threadIdx.x;
  const int w = tid >> 6, lane = tid & 63;
  const int lane15 = lane & 15, quad = lane >> 4;
  const int wr = w >> 1, wc = w & 1;
  const long m0 = (long)blockIdx.y * 128;
  const int n0 = blockIdx.x * 128;
  const int lrow = lane >> 2;        // 0..15 within staging shot
  const int lk8  = (lane & 3) * 8;   // k element offset within 32

  f32x4 acc[4][4];
  #pragma unroll
  for (int i = 0; i < 4; i++)
    #pragma unroll
    for (int j = 0; j < 4; j++) acc[i][j] = (f32x4){0.f, 0.f, 0.f, 0.f};

  const int nk = K >> 5;
  for (int kb = 0; kb < nk; kb++){
    const int k0 = kb << 5;
    __syncthreads();
    #pragma unroll
    for (int s = 0; s < 2; s++){
      int m = w * 32 + s * 16 + lrow;
      async16(A + ((m0 + m) * K + k0 + lk8), &As[(w * 32 + s * 16) * 32]);
    }
    #pragma unroll
    for (int s = 0; s < 2; s++){
      int n = w * 32 + s * 16 + lrow;
      async16(Bt + ((long)(n0 + n) * K + k0 + lk8), &Bs[(w * 32 + s * 16) * 32]);
    }
    __builtin_amdgcn_s_waitcnt(0);
    __syncthreads();

    bf16x8 af[4], bf[4];
    #pragma unroll
    for (int i = 0; i < 4; i++)
      af[i] = *(const bf16x8*)&As[(wr * 64 + i * 16 + lane15) * 32 + quad * 8];
    #pragma unroll
    for (int j = 0; j < 4; j++)
      bf[j] = *(const bf16x8*)&Bs[(wc * 64 + j * 16 + lane15) * 32 + quad * 8];
    #pragma unroll
    for (int i = 0; i < 4; i++)
      #pragma unroll
      for (int j = 0; j < 4; j++)
        acc[i][j] = __builtin_amdgcn_mfma_f32_16x16x32_bf16(af[i], bf[j], acc[i][j], 0, 0, 0);
  }

  // ---------------- epilogue ----------------
  if (MODE == 0){
    #pragma unroll
    for (int i = 0; i < 4; i++){
      int row_l = wr * 64 + i * 16 + quad * 4;
      #pragma unroll
      for (int j = 0; j < 4; j++){
        int col = n0 + wc * 64 + j * 16 + lane15;
        float b = bias[col];
        #pragma unroll
        for (int r = 0; r < 4; r++){
          float v = acc[i][j][r] + b;
          if (TANH) v = tanhf(v);
          outb[(m0 + row_l + r) * N + col] = f2bf(v);
        }
      }
    }
  } else if (MODE == 1){
    int f = *flagp;
    #pragma unroll
    for (int i = 0; i < 4; i++){
      int row_l = wr * 64 + i * 16 + quad * 4;
      #pragma unroll
      for (int j = 0; j < 4; j++){
        int col = wc * 64 + j * 16 + lane15;   // N==128, n0==0
        float b = bias[col];
        #pragma unroll
        for (int r = 0; r < 4; r++){
          float v = acc[i][j][r] + b;
          long idx = (m0 + row_l + r) * 128 + col;
          outf[idx] = v;
          ushort_t bb = f2bf(v);
          outb[idx] = bb;
          if (f) ((ushort_t*)dout)[dout_off + idx] = bb;
          else   ((float*)dout)[dout_off + idx] = v;
        }
      }
    }
  } else if (MODE == 2){
    int f = *flagp;
    #pragma unroll
    for (int i = 0; i < 4; i++){
      int row_l = wr * 64 + i * 16 + quad * 4;
      #pragma unroll
      for (int j = 0; j < 4; j++){
        int col = n0 + wc * 64 + j * 16 + lane15;
        float b = bias[col];
        #pragma unroll
        for (int r = 0; r < 4; r++){
          float v = acc[i][j][r] + b;
          long idx = (m0 + row_l + r) * N + col;
          if (f) ((ushort_t*)dout)[dout_off + idx] = f2bf(v);
          else   ((float*)dout)[dout_off + idx] = v;
        }
      }
    }
  } else { // MODE 3: VQ score + per-row argmax over this 128-col block
    float bestv[16]; int bestc[16];
    #pragma unroll
    for (int i = 0; i < 4; i++){
      #pragma unroll
      for (int r = 0; r < 4; r++){
        float best = -1e30f; int bcol = 0;
        #pragma unroll
        for (int j = 0; j < 4; j++){
          int col = n0 + wc * 64 + j * 16 + lane15;
          float v = acc[i][j][r] - 0.5f * enorm[col];
          if (v > best){ best = v; bcol = col; }
        }
        #pragma unroll
        for (int off = 1; off < 16; off <<= 1){
          float ov = __shfl_xor(best, off, 64);
          int   oc = __shfl_xor(bcol, off, 64);
          if (ov > best || (ov == best && oc < bcol)){ best = ov; bcol = oc; }
        }
        bestv[i * 4 + r] = best; bestc[i * 4 + r] = bcol;
      }
    }
    __syncthreads();                  // LDS free for reuse now
    float* lv = (float*)As;           // [128][2]
    int*   li = (int*)Bs;             // [128][2]
    #pragma unroll
    for (int i = 0; i < 4; i++)
      #pragma unroll
      for (int r = 0; r < 4; r++){
        int row_l = wr * 64 + i * 16 + quad * 4 + r;
        if (lane15 == 0){ lv[row_l * 2 + wc] = bestv[i * 4 + r]; li[row_l * 2 + wc] = bestc[i * 4 + r]; }
      }
    __syncthreads();
    if (tid < 128){
      float v0 = lv[tid * 2], v1 = lv[tid * 2 + 1];
      int   c0 = li[tid * 2], c1 = li[tid * 2 + 1];
      float bv; int bc;
      if (v1 > v0 || (v1 == v0 && c1 < c0)){ bv = v1; bc = c1; } else { bv = v0; bc = c0; }
      long row = m0 + tid;
      cand_v[row * 8 + blockIdx.x] = bv;
      cand_i[row * 8 + blockIdx.x] = bc;
    }
  }
}

// =====================================================================
// VQ finalize: per-row argmax over 8 candidates, gather code, emit
// quantized (decoder input, bf16), z_q to d_out, loss partial sums.
// grid 16384, block 256 (2 rows / block)
// =====================================================================
__global__ __launch_bounds__(256)
void k_vqfin(const float* __restrict__ cand_v, const int* __restrict__ cand_i,
             const float* __restrict__ zf, const ushort_t* __restrict__ embb,
             ushort_t* __restrict__ qb, void* __restrict__ dout, long zq_off,
             float* __restrict__ loss_acc, const int* __restrict__ flagp)
{
  int f = *flagp;
  long row = (long)blockIdx.x * 2 + (threadIdx.x >> 7);
  int d = threadIdx.x & 127;
  float best = -1e30f; int bi = 0;
  #pragma unroll
  for (int nb = 0; nb < 8; nb++){
    float v = cand_v[row * 8 + nb]; int c = cand_i[row * 8 + nb];
    if (v > best || (v == best && c < bi)){ best = v; bi = c; }
  }
  ushort_t qbits = embb[(long)bi * LATENT + d];
  float q = bf2f(qbits);
  long idx = row * LATENT + d;
  qb[idx] = qbits;
  if (f) ((ushort_t*)dout)[zq_off + idx] = qbits;
  else   ((float*)dout)[zq_off + idx] = q;
  float diff = zf[idx] - q;
  float p = diff * diff;
  #pragma unroll
  for (int off = 32; off; off >>= 1) p += __shfl_down(p, off, 64);
  __shared__ float red[4];
  if ((threadIdx.x & 63) == 0) red[threadIdx.x >> 6] = p;
  __syncthreads();
  if (threadIdx.x == 0) atomicAdd(loss_acc, red[0] + red[1] + red[2] + red[3]);
}

__global__ void k_lossfin(const float* __restrict__ loss_acc, void* __restrict__ dout,
                          long off, const int* __restrict__ flagp){
  if (threadIdx.x == 0){
    float v = 1.25f * loss_acc[0] / (float)((long)BB * LATENT);
    if (*flagp) ((ushort_t*)dout)[off] = f2bf(v);
    else        ((float*)dout)[off] = v;
  }
}

// =====================================================================
extern "C" void kernel_launch(void* const* d_in, const int* in_sizes, int n_in,
                              void* d_out, int out_size, void* d_ws, size_t ws_size,
                              hipStream_t stream)
{
  (void)in_sizes; (void)n_in; (void)out_size; (void)ws_size;
  const void* action = d_in[1];
  const void* eW0 = d_in[2];  const void* eb0 = d_in[3];
  const void* eW1 = d_in[4];  const void* eb1 = d_in[5];
  const void* eW2 = d_in[6];  const void* eb2 = d_in[7];
  const void* emb = d_in[8];
  const void* dW0 = d_in[9];  const void* db0 = d_in[10];
  const void* dW1 = d_in[11]; const void* db1 = d_in[12];
  const void* dW2 = d_in[13]; const void* db2 = d_in[14];

  char* ws = (char*)d_ws;
  size_t off = 0;
  auto alloc = [&](size_t bytes)->char*{
    char* p = ws + off; off += bytes; off = (off + 255) & ~((size_t)255); return p;
  };
  int*      flag     = (int*)  alloc(4);
  float*    loss_acc = (float*)alloc(4);
  float*    biasf    = (float*)alloc(6 * 1024 * 4);
  float*    enorm    = (float*)alloc(KCODES * 4);
  ushort_t* eW0t = (ushort_t*)alloc((size_t)HID * INDIM * 2);     // [1024][256]
  ushort_t* eW1t = (ushort_t*)alloc((size_t)HID * HID * 2);       // [1024][1024]
  ushort_t* eW2t = (ushort_t*)alloc((size_t)LATENT * HID * 2);    // [128][1024]
  ushort_t* embb = (ushort_t*)alloc((size_t)KCODES * LATENT * 2); // [1024][128]
  ushort_t* dW0t = (ushort_t*)alloc((size_t)HID * LATENT * 2);    // [1024][128]
  ushort_t* dW1t = (ushort_t*)alloc((size_t)HID * HID * 2);       // [1024][1024]
  ushort_t* dW2t = (ushort_t*)alloc((size_t)INDIM * HID * 2);     // [256][1024]
  ushort_t* act0 = (ushort_t*)alloc((size_t)BB * INDIM * 2);
  ushort_t* hA   = (ushort_t*)alloc((size_t)BB * HID * 2);
  ushort_t* hB   = (ushort_t*)alloc((size_t)BB * HID * 2);
  float*    zf32 = (float*)   alloc((size_t)BB * LATENT * 4);
  ushort_t* zb16 = (ushort_t*)alloc((size_t)BB * LATENT * 2);
  ushort_t* qb16 = (ushort_t*)alloc((size_t)BB * LATENT * 2);
  float*    cand_v = (float*) alloc((size_t)BB * 8 * 4);
  int*      cand_i = (int*)   alloc((size_t)BB * 8 * 4);

  const long z_off  = (long)BB * INDIM;            // 8388608
  const long zq_off = z_off + (long)BB * LATENT;   // 12582912
  const long l_off  = zq_off + (long)BB * LATENT;  // 16777216

  // ---- prep ----
  k_sniff<<<1, 64, 0, stream>>>((const ushort_t*)action, flag, loss_acc);
  k_cvt<<<256, 256, 0, stream>>>(action, act0, BB * INDIM, flag);
  k_tcvt<<<dim3(HID / 32, INDIM / 32), 256, 0, stream>>>(eW0, eW0t, INDIM, HID, flag);
  k_tcvt<<<dim3(HID / 32, HID / 32),  256, 0, stream>>>(eW1, eW1t, HID, HID, flag);
  k_tcvt<<<dim3(LATENT / 32, HID / 32), 256, 0, stream>>>(eW2, eW2t, HID, LATENT, flag);
  k_tcvt<<<dim3(HID / 32, LATENT / 32), 256, 0, stream>>>(dW0, dW0t, LATENT, HID, flag);
  k_tcvt<<<dim3(HID / 32, HID / 32),  256, 0, stream>>>(dW1, dW1t, HID, HID, flag);
  k_tcvt<<<dim3(INDIM / 32, HID / 32), 256, 0, stream>>>(dW2, dW2t, HID, INDIM, flag);
  k_cvt<<<128, 256, 0, stream>>>(emb, embb, KCODES * LATENT, flag);
  k_bias<<<24, 256, 0, stream>>>(eb0, eb1, eb2, db0, db1, db2, biasf, flag);
  k_enorm<<<4, 256, 0, stream>>>(embb, enorm);

  // ---- encoder ----
  k_gemm<0, 1><<<dim3(8, 256), 256, 0, stream>>>(act0, eW0t, biasf + 0, BB, HID, INDIM,
      hA, nullptr, nullptr, 0, nullptr, nullptr, nullptr, flag);
  k_gemm<0, 1><<<dim3(8, 256), 256, 0, stream>>>(hA, eW1t, biasf + 1024, BB, HID, HID,
      hB, nullptr, nullptr, 0, nullptr, nullptr, nullptr, flag);
  k_gemm<1, 0><<<dim3(1, 256), 256, 0, stream>>>(hB, eW2t, biasf + 2048, BB, LATENT, HID,
      zb16, zf32, d_out, z_off, nullptr, nullptr, nullptr, flag);

  // ---- VQ ----
  k_gemm<3, 0><<<dim3(8, 256), 256, 0, stream>>>(zb16, embb, nullptr, BB, KCODES, LATENT,
      nullptr, nullptr, nullptr, 0, enorm, cand_v, cand_i, flag);
  k_vqfin<<<BB / 2, 256, 0, stream>>>(cand_v, cand_i, zf32, embb, qb16, d_out, zq_off,
      loss_acc, flag);

  // ---- decoder ----
  k_gemm<0, 1><<<dim3(8, 256), 256, 0, stream>>>(qb16, dW0t, biasf + 3072, BB, HID, LATENT,
      hA, nullptr, nullptr, 0, nullptr, nullptr, nullptr, flag);
  k_gemm<0, 1><<<dim3(8, 256), 256, 0, stream>>>(hA, dW1t, biasf + 4096, BB, HID, HID,
      hB, nullptr, nullptr, 0, nullptr, nullptr, nullptr, flag);
  k_gemm<2, 0><<<dim3(2, 256), 256, 0, stream>>>(hB, dW2t, biasf + 5120, BB, INDIM, HID,
      nullptr, nullptr, d_out, 0, nullptr, nullptr, nullptr, flag);

  k_lossfin<<<1, 64, 0, stream>>>(loss_acc, d_out, l_off, flag);
}

// Round 2
// 720.546 us; speedup vs baseline: 1.2396x; 1.2396x over previous
//
#include <hip/hip_runtime.h>
#include <stdint.h>
#include <math.h>

#define DEVI __device__ __forceinline__
typedef unsigned short ushort_t;
typedef __attribute__((ext_vector_type(8))) __bf16 bf16x8;
typedef __attribute__((ext_vector_type(4))) float f32x4;

// ---------- scalar bf16 helpers (RNE, matches HW/harness encoding) ----------
DEVI float bf2f(ushort_t b){ union{uint32_t u; float f;} c; c.u = ((uint32_t)b) << 16; return c.f; }
DEVI ushort_t f2bf(float f){ union{float f; uint32_t u;} c; c.f = f; uint32_t u = c.u;
                             u += 0x7fffu + ((u >> 16) & 1u); return (ushort_t)(u >> 16); }

// ---------- async global->LDS (16B per lane, dest = wave-uniform base + lane*16) ----------
DEVI void async16(const ushort_t* g, ushort_t* l){
  __builtin_amdgcn_global_load_lds((const __attribute__((address_space(1))) void*)g,
                                   (__attribute__((address_space(3))) void*)l, 16, 0, 0);
}

// ---------- problem constants ----------
#define BB 32768
#define INDIM 256
#define LATENT 128
#define HID 1024
#define KCODES 1024

// =====================================================================
// dtype sniffer: if inputs are fp32, every other bf16-half of `action`
// is fp32-mantissa garbage with a uniform-random exponent.
// flag = 1 -> buffers are bf16 ; flag = 0 -> fp32
// =====================================================================
__global__ void k_sniff(const ushort_t* __restrict__ act, int* flag){
  if (threadIdx.x == 0){
    int bad = 0;
    for (int i = 0; i < 256; i++){
      float v = bf2f(act[i]);
      float a = fabsf(v);
      if (!(a <= 16.0f) || (a > 0.0f && a < 9.5e-7f)) bad++;
    }
    flag[0] = (bad >= 8) ? 0 : 1;
  }
}

// convert (no transpose) to bf16 bits
__global__ void k_cvt(const void* __restrict__ src, ushort_t* __restrict__ dst, int n,
                      const int* __restrict__ flagp){
  int f = *flagp;
  for (int i = blockIdx.x * blockDim.x + threadIdx.x; i < n; i += gridDim.x * blockDim.x){
    dst[i] = f ? ((const ushort_t*)src)[i] : f2bf(((const float*)src)[i]);
  }
}

// convert + transpose: src[R][C] -> dst[C][R] (bf16). grid(C/32, R/32), block 256
__global__ void k_tcvt(const void* __restrict__ src, ushort_t* __restrict__ dst, int R, int C,
                       const int* __restrict__ flagp){
  __shared__ ushort_t tile[32][33];
  int f = *flagp;
  int tx = threadIdx.x & 31, ty = threadIdx.x >> 5;
  int c = blockIdx.x * 32 + tx;
  #pragma unroll
  for (int ii = 0; ii < 4; ii++){
    int r = blockIdx.y * 32 + ty + ii * 8;
    long idx = (long)r * C + c;
    tile[ty + ii * 8][tx] = f ? ((const ushort_t*)src)[idx] : f2bf(((const float*)src)[idx]);
  }
  __syncthreads();
  #pragma unroll
  for (int ii = 0; ii < 4; ii++){
    int cc = blockIdx.x * 32 + ty + ii * 8;
    dst[(long)cc * R + blockIdx.y * 32 + tx] = tile[tx][ty + ii * 8];
  }
}

// all 6 biases -> fp32, 1024-float slots. grid 24 x 256
__global__ void k_bias(const void* s0, const void* s1, const void* s2,
                       const void* s3, const void* s4, const void* s5,
                       float* __restrict__ d, const int* __restrict__ flagp){
  int f = *flagp;
  int i = blockIdx.x * blockDim.x + threadIdx.x;
  int seg = i >> 10, off = i & 1023;
  const void* sp; int n;
  switch (seg){
    case 0: sp = s0; n = 1024; break;
    case 1: sp = s1; n = 1024; break;
    case 2: sp = s2; n = 128;  break;
    case 3: sp = s3; n = 1024; break;
    case 4: sp = s4; n = 1024; break;
    default: sp = s5; n = 256; break;
  }
  if (off < n)
    d[seg * 1024 + off] = f ? bf2f(((const ushort_t*)sp)[off]) : ((const float*)sp)[off];
}

// ||e_c||^2 from bf16 codebook. grid 4 x 256
__global__ void k_enorm(const ushort_t* __restrict__ embb, float* __restrict__ enorm){
  int c = blockIdx.x * blockDim.x + threadIdx.x;
  if (c < KCODES){
    float s = 0.f;
    for (int d = 0; d < LATENT; d++){ float v = bf2f(embb[c * LATENT + d]); s += v * v; }
    enorm[c] = s;
  }
}

// =====================================================================
// generic MFMA GEMM: C[M,N] = A[M,K] @ Bt[N,K]^T (+bias) (+tanh)
// 128x128 tile / workgroup, 4 waves in 2x2, each 4x4 of 16x16x32 MFMAs.
// MODE 0: out = bf16 activation buffer (TANH optional)
// MODE 1: z: fp32 buf + bf16 buf + d_out (flag dtype)
// MODE 2: recon: d_out only (flag dtype)
// MODE 3: VQ scores: acc - 0.5*enorm[col], per-row argmax -> candidates
// =====================================================================
template<int MODE, int TANH>
__global__ __launch_bounds__(256)
void k_gemm(const ushort_t* __restrict__ A, const ushort_t* __restrict__ Bt,
            const float* __restrict__ bias, int M, int N, int K,
            ushort_t* __restrict__ outb, float* __restrict__ outf,
            void* __restrict__ dout, long dout_off,
            const float* __restrict__ enorm,
            float* __restrict__ cand_v, int* __restrict__ cand_i,
            const int* __restrict__ flagp)
{
  __shared__ __align__(16) ushort_t As[128 * 32];
  __shared__ __align__(16) ushort_t Bs[128 * 32];
  const int tid = threadIdx.x;
  const int w = tid >> 6, lane = tid & 63;
  const int lane15 = lane & 15, quad = lane >> 4;
  const int wr = w >> 1, wc = w & 1;
  const long m0 = (long)blockIdx.y * 128;
  const int n0 = blockIdx.x * 128;
  const int lrow = lane >> 2;        // 0..15 within staging shot
  const int lk8  = (lane & 3) * 8;   // k element offset within 32

  f32x4 acc[4][4];
  #pragma unroll
  for (int i = 0; i < 4; i++)
    #pragma unroll
    for (int j = 0; j < 4; j++) acc[i][j] = (f32x4){0.f, 0.f, 0.f, 0.f};

  const int nk = K >> 5;
  for (int kb = 0; kb < nk; kb++){
    const int k0 = kb << 5;
    __syncthreads();
    #pragma unroll
    for (int s = 0; s < 2; s++){
      int m = w * 32 + s * 16 + lrow;
      async16(A + ((m0 + m) * K + k0 + lk8), &As[(w * 32 + s * 16) * 32]);
    }
    #pragma unroll
    for (int s = 0; s < 2; s++){
      int n = w * 32 + s * 16 + lrow;
      async16(Bt + ((long)(n0 + n) * K + k0 + lk8), &Bs[(w * 32 + s * 16) * 32]);
    }
    __builtin_amdgcn_s_waitcnt(0);
    __syncthreads();

    bf16x8 af[4], bf[4];
    #pragma unroll
    for (int i = 0; i < 4; i++)
      af[i] = *(const bf16x8*)&As[(wr * 64 + i * 16 + lane15) * 32 + quad * 8];
    #pragma unroll
    for (int j = 0; j < 4; j++)
      bf[j] = *(const bf16x8*)&Bs[(wc * 64 + j * 16 + lane15) * 32 + quad * 8];
    #pragma unroll
    for (int i = 0; i < 4; i++)
      #pragma unroll
      for (int j = 0; j < 4; j++)
        acc[i][j] = __builtin_amdgcn_mfma_f32_16x16x32_bf16(af[i], bf[j], acc[i][j], 0, 0, 0);
  }

  // ---------------- epilogue ----------------
  if (MODE == 0){
    #pragma unroll
    for (int i = 0; i < 4; i++){
      int row_l = wr * 64 + i * 16 + quad * 4;
      #pragma unroll
      for (int j = 0; j < 4; j++){
        int col = n0 + wc * 64 + j * 16 + lane15;
        float b = bias[col];
        #pragma unroll
        for (int r = 0; r < 4; r++){
          float v = acc[i][j][r] + b;
          if (TANH) v = tanhf(v);
          outb[(m0 + row_l + r) * N + col] = f2bf(v);
        }
      }
    }
  } else if (MODE == 1){
    int f = *flagp;
    #pragma unroll
    for (int i = 0; i < 4; i++){
      int row_l = wr * 64 + i * 16 + quad * 4;
      #pragma unroll
      for (int j = 0; j < 4; j++){
        int col = wc * 64 + j * 16 + lane15;   // N==128, n0==0
        float b = bias[col];
        #pragma unroll
        for (int r = 0; r < 4; r++){
          float v = acc[i][j][r] + b;
          long idx = (m0 + row_l + r) * 128 + col;
          outf[idx] = v;
          ushort_t bb = f2bf(v);
          outb[idx] = bb;
          if (f) ((ushort_t*)dout)[dout_off + idx] = bb;
          else   ((float*)dout)[dout_off + idx] = v;
        }
      }
    }
  } else if (MODE == 2){
    int f = *flagp;
    #pragma unroll
    for (int i = 0; i < 4; i++){
      int row_l = wr * 64 + i * 16 + quad * 4;
      #pragma unroll
      for (int j = 0; j < 4; j++){
        int col = n0 + wc * 64 + j * 16 + lane15;
        float b = bias[col];
        #pragma unroll
        for (int r = 0; r < 4; r++){
          float v = acc[i][j][r] + b;
          long idx = (m0 + row_l + r) * N + col;
          if (f) ((ushort_t*)dout)[dout_off + idx] = f2bf(v);
          else   ((float*)dout)[dout_off + idx] = v;
        }
      }
    }
  } else { // MODE 3: VQ score + per-row argmax over this 128-col block
    float bestv[16]; int bestc[16];
    #pragma unroll
    for (int i = 0; i < 4; i++){
      #pragma unroll
      for (int r = 0; r < 4; r++){
        float best = -1e30f; int bcol = 0;
        #pragma unroll
        for (int j = 0; j < 4; j++){
          int col = n0 + wc * 64 + j * 16 + lane15;
          float v = acc[i][j][r] - 0.5f * enorm[col];
          if (v > best){ best = v; bcol = col; }
        }
        #pragma unroll
        for (int off = 1; off < 16; off <<= 1){
          float ov = __shfl_xor(best, off, 64);
          int   oc = __shfl_xor(bcol, off, 64);
          if (ov > best || (ov == best && oc < bcol)){ best = ov; bcol = oc; }
        }
        bestv[i * 4 + r] = best; bestc[i * 4 + r] = bcol;
      }
    }
    __syncthreads();                  // LDS free for reuse now
    float* lv = (float*)As;           // [128][2]
    int*   li = (int*)Bs;             // [128][2]
    #pragma unroll
    for (int i = 0; i < 4; i++)
      #pragma unroll
      for (int r = 0; r < 4; r++){
        int row_l = wr * 64 + i * 16 + quad * 4 + r;
        if (lane15 == 0){ lv[row_l * 2 + wc] = bestv[i * 4 + r]; li[row_l * 2 + wc] = bestc[i * 4 + r]; }
      }
    __syncthreads();
    if (tid < 128){
      float v0 = lv[tid * 2], v1 = lv[tid * 2 + 1];
      int   c0 = li[tid * 2], c1 = li[tid * 2 + 1];
      float bv; int bc;
      if (v1 > v0 || (v1 == v0 && c1 < c0)){ bv = v1; bc = c1; } else { bv = v0; bc = c0; }
      long row = m0 + tid;
      cand_v[row * 8 + blockIdx.x] = bv;
      cand_i[row * 8 + blockIdx.x] = bc;
    }
  }
}

// =====================================================================
// VQ finalize: per-row argmax over 8 candidates, gather code, emit
// quantized (decoder input, bf16), z_q to d_out, loss PARTIAL per block
// (no same-address atomics — they serialized at 13 ns each in R1).
// grid 16384, block 256 (2 rows / block)
// =====================================================================
__global__ __launch_bounds__(256)
void k_vqfin(const float* __restrict__ cand_v, const int* __restrict__ cand_i,
             const float* __restrict__ zf, const ushort_t* __restrict__ embb,
             ushort_t* __restrict__ qb, void* __restrict__ dout, long zq_off,
             float* __restrict__ loss_part, const int* __restrict__ flagp)
{
  int f = *flagp;
  long row = (long)blockIdx.x * 2 + (threadIdx.x >> 7);
  int d = threadIdx.x & 127;
  float best = -1e30f; int bi = 0;
  #pragma unroll
  for (int nb = 0; nb < 8; nb++){
    float v = cand_v[row * 8 + nb]; int c = cand_i[row * 8 + nb];
    if (v > best || (v == best && c < bi)){ best = v; bi = c; }
  }
  ushort_t qbits = embb[(long)bi * LATENT + d];
  float q = bf2f(qbits);
  long idx = row * LATENT + d;
  qb[idx] = qbits;
  if (f) ((ushort_t*)dout)[zq_off + idx] = qbits;
  else   ((float*)dout)[zq_off + idx] = q;
  float diff = zf[idx] - q;
  float p = diff * diff;
  #pragma unroll
  for (int off = 32; off; off >>= 1) p += __shfl_down(p, off, 64);
  __shared__ float red[4];
  if ((threadIdx.x & 63) == 0) red[threadIdx.x >> 6] = p;
  __syncthreads();
  if (threadIdx.x == 0) loss_part[blockIdx.x] = red[0] + red[1] + red[2] + red[3];
}

// reduce 16384 partials -> final loss scalar. grid 1, block 256
__global__ __launch_bounds__(256)
void k_lossfin(const float* __restrict__ loss_part, void* __restrict__ dout,
               long off, const int* __restrict__ flagp){
  __shared__ float red[4];
  float s = 0.f;
  for (int i = threadIdx.x; i < BB / 2; i += 256) s += loss_part[i];
  #pragma unroll
  for (int o = 32; o; o >>= 1) s += __shfl_down(s, o, 64);
  if ((threadIdx.x & 63) == 0) red[threadIdx.x >> 6] = s;
  __syncthreads();
  if (threadIdx.x == 0){
    float v = 1.25f * (red[0] + red[1] + red[2] + red[3]) / (float)((long)BB * LATENT);
    if (*flagp) ((ushort_t*)dout)[off] = f2bf(v);
    else        ((float*)dout)[off] = v;
  }
}

// =====================================================================
extern "C" void kernel_launch(void* const* d_in, const int* in_sizes, int n_in,
                              void* d_out, int out_size, void* d_ws, size_t ws_size,
                              hipStream_t stream)
{
  (void)in_sizes; (void)n_in; (void)out_size; (void)ws_size;
  const void* action = d_in[1];
  const void* eW0 = d_in[2];  const void* eb0 = d_in[3];
  const void* eW1 = d_in[4];  const void* eb1 = d_in[5];
  const void* eW2 = d_in[6];  const void* eb2 = d_in[7];
  const void* emb = d_in[8];
  const void* dW0 = d_in[9];  const void* db0 = d_in[10];
  const void* dW1 = d_in[11]; const void* db1 = d_in[12];
  const void* dW2 = d_in[13]; const void* db2 = d_in[14];

  char* ws = (char*)d_ws;
  size_t off = 0;
  auto alloc = [&](size_t bytes)->char*{
    char* p = ws + off; off += bytes; off = (off + 255) & ~((size_t)255); return p;
  };
  int*      flag     = (int*)  alloc(4);
  float*    biasf    = (float*)alloc(6 * 1024 * 4);
  float*    enorm    = (float*)alloc(KCODES * 4);
  ushort_t* eW0t = (ushort_t*)alloc((size_t)HID * INDIM * 2);     // [1024][256]
  ushort_t* eW1t = (ushort_t*)alloc((size_t)HID * HID * 2);       // [1024][1024]
  ushort_t* eW2t = (ushort_t*)alloc((size_t)LATENT * HID * 2);    // [128][1024]
  ushort_t* embb = (ushort_t*)alloc((size_t)KCODES * LATENT * 2); // [1024][128]
  ushort_t* dW0t = (ushort_t*)alloc((size_t)HID * LATENT * 2);    // [1024][128]
  ushort_t* dW1t = (ushort_t*)alloc((size_t)HID * HID * 2);       // [1024][1024]
  ushort_t* dW2t = (ushort_t*)alloc((size_t)INDIM * HID * 2);     // [256][1024]
  ushort_t* act0 = (ushort_t*)alloc((size_t)BB * INDIM * 2);
  ushort_t* hA   = (ushort_t*)alloc((size_t)BB * HID * 2);
  ushort_t* hB   = (ushort_t*)alloc((size_t)BB * HID * 2);
  float*    zf32 = (float*)   alloc((size_t)BB * LATENT * 4);
  ushort_t* zb16 = (ushort_t*)alloc((size_t)BB * LATENT * 2);
  ushort_t* qb16 = (ushort_t*)alloc((size_t)BB * LATENT * 2);
  float*    cand_v = (float*) alloc((size_t)BB * 8 * 4);
  int*      cand_i = (int*)   alloc((size_t)BB * 8 * 4);
  float*    loss_part = (float*)alloc((size_t)(BB / 2) * 4);

  const long z_off  = (long)BB * INDIM;            // 8388608
  const long zq_off = z_off + (long)BB * LATENT;   // 12582912
  const long l_off  = zq_off + (long)BB * LATENT;  // 16777216

  // ---- prep ----
  k_sniff<<<1, 64, 0, stream>>>((const ushort_t*)action, flag);
  k_cvt<<<256, 256, 0, stream>>>(action, act0, BB * INDIM, flag);
  k_tcvt<<<dim3(HID / 32, INDIM / 32), 256, 0, stream>>>(eW0, eW0t, INDIM, HID, flag);
  k_tcvt<<<dim3(HID / 32, HID / 32),  256, 0, stream>>>(eW1, eW1t, HID, HID, flag);
  k_tcvt<<<dim3(LATENT / 32, HID / 32), 256, 0, stream>>>(eW2, eW2t, HID, LATENT, flag);
  k_tcvt<<<dim3(HID / 32, LATENT / 32), 256, 0, stream>>>(dW0, dW0t, LATENT, HID, flag);
  k_tcvt<<<dim3(HID / 32, HID / 32),  256, 0, stream>>>(dW1, dW1t, HID, HID, flag);
  k_tcvt<<<dim3(INDIM / 32, HID / 32), 256, 0, stream>>>(dW2, dW2t, HID, INDIM, flag);
  k_cvt<<<128, 256, 0, stream>>>(emb, embb, KCODES * LATENT, flag);
  k_bias<<<24, 256, 0, stream>>>(eb0, eb1, eb2, db0, db1, db2, biasf, flag);
  k_enorm<<<4, 256, 0, stream>>>(embb, enorm);

  // ---- encoder ----
  k_gemm<0, 1><<<dim3(8, 256), 256, 0, stream>>>(act0, eW0t, biasf + 0, BB, HID, INDIM,
      hA, nullptr, nullptr, 0, nullptr, nullptr, nullptr, flag);
  k_gemm<0, 1><<<dim3(8, 256), 256, 0, stream>>>(hA, eW1t, biasf + 1024, BB, HID, HID,
      hB, nullptr, nullptr, 0, nullptr, nullptr, nullptr, flag);
  k_gemm<1, 0><<<dim3(1, 256), 256, 0, stream>>>(hB, eW2t, biasf + 2048, BB, LATENT, HID,
      zb16, zf32, d_out, z_off, nullptr, nullptr, nullptr, flag);

  // ---- VQ ----
  k_gemm<3, 0><<<dim3(8, 256), 256, 0, stream>>>(zb16, embb, nullptr, BB, KCODES, LATENT,
      nullptr, nullptr, nullptr, 0, enorm, cand_v, cand_i, flag);
  k_vqfin<<<BB / 2, 256, 0, stream>>>(cand_v, cand_i, zf32, embb, qb16, d_out, zq_off,
      loss_part, flag);

  // ---- decoder ----
  k_gemm<0, 1><<<dim3(8, 256), 256, 0, stream>>>(qb16, dW0t, biasf + 3072, BB, HID, LATENT,
      hA, nullptr, nullptr, 0, nullptr, nullptr, nullptr, flag);
  k_gemm<0, 1><<<dim3(8, 256), 256, 0, stream>>>(hA, dW1t, biasf + 4096, BB, HID, HID,
      hB, nullptr, nullptr, 0, nullptr, nullptr, nullptr, flag);
  k_gemm<2, 0><<<dim3(2, 256), 256, 0, stream>>>(hB, dW2t, biasf + 5120, BB, INDIM, HID,
      nullptr, nullptr, d_out, 0, nullptr, nullptr, nullptr, flag);

  k_lossfin<<<1, 256, 0, stream>>>(loss_part, d_out, l_off, flag);
}

// Round 3
// 678.579 us; speedup vs baseline: 1.3162x; 1.0618x over previous
//
#include <hip/hip_runtime.h>
#include <stdint.h>
#include <math.h>

#define DEVI __device__ __forceinline__
typedef unsigned short ushort_t;
typedef __attribute__((ext_vector_type(8))) __bf16 bf16x8;
typedef __attribute__((ext_vector_type(4))) float f32x4;

// ---------- scalar bf16 helpers (RNE, matches HW/harness encoding) ----------
DEVI float bf2f(ushort_t b){ union{uint32_t u; float f;} c; c.u = ((uint32_t)b) << 16; return c.f; }
DEVI ushort_t f2bf(float f){ union{float f; uint32_t u;} c; c.f = f; uint32_t u = c.u;
                             u += 0x7fffu + ((u >> 16) & 1u); return (ushort_t)(u >> 16); }

// ---------- async global->LDS (16B per lane, dest = wave-uniform base + lane*16) ----------
DEVI void async16(const ushort_t* g, ushort_t* l){
  __builtin_amdgcn_global_load_lds((const __attribute__((address_space(1))) void*)g,
                                   (__attribute__((address_space(3))) void*)l, 16, 0, 0);
}

// ---------- problem constants ----------
#define BB 32768
#define INDIM 256
#define LATENT 128
#define HID 1024
#define KCODES 1024

// =====================================================================
// dtype sniffer: flag = 1 -> buffers are bf16 ; flag = 0 -> fp32
// =====================================================================
__global__ void k_sniff(const ushort_t* __restrict__ act, int* flag){
  if (threadIdx.x == 0){
    int bad = 0;
    for (int i = 0; i < 256; i++){
      float v = bf2f(act[i]);
      float a = fabsf(v);
      if (!(a <= 16.0f) || (a > 0.0f && a < 9.5e-7f)) bad++;
    }
    flag[0] = (bad >= 8) ? 0 : 1;
  }
}

// convert (no transpose) to bf16 bits
__global__ void k_cvt(const void* __restrict__ src, ushort_t* __restrict__ dst, int n,
                      const int* __restrict__ flagp){
  int f = *flagp;
  for (int i = blockIdx.x * blockDim.x + threadIdx.x; i < n; i += gridDim.x * blockDim.x){
    dst[i] = f ? ((const ushort_t*)src)[i] : f2bf(((const float*)src)[i]);
  }
}

// convert + transpose: src[R][C] -> dst[C][R] (bf16). grid(C/32, R/32), block 256
__global__ void k_tcvt(const void* __restrict__ src, ushort_t* __restrict__ dst, int R, int C,
                       const int* __restrict__ flagp){
  __shared__ ushort_t tile[32][33];
  int f = *flagp;
  int tx = threadIdx.x & 31, ty = threadIdx.x >> 5;
  int c = blockIdx.x * 32 + tx;
  #pragma unroll
  for (int ii = 0; ii < 4; ii++){
    int r = blockIdx.y * 32 + ty + ii * 8;
    long idx = (long)r * C + c;
    tile[ty + ii * 8][tx] = f ? ((const ushort_t*)src)[idx] : f2bf(((const float*)src)[idx]);
  }
  __syncthreads();
  #pragma unroll
  for (int ii = 0; ii < 4; ii++){
    int cc = blockIdx.x * 32 + ty + ii * 8;
    dst[(long)cc * R + blockIdx.y * 32 + tx] = tile[tx][ty + ii * 8];
  }
}

// all 6 biases -> fp32, 1024-float slots. grid 24 x 256
__global__ void k_bias(const void* s0, const void* s1, const void* s2,
                       const void* s3, const void* s4, const void* s5,
                       float* __restrict__ d, const int* __restrict__ flagp){
  int f = *flagp;
  int i = blockIdx.x * blockDim.x + threadIdx.x;
  int seg = i >> 10, off = i & 1023;
  const void* sp; int n;
  switch (seg){
    case 0: sp = s0; n = 1024; break;
    case 1: sp = s1; n = 1024; break;
    case 2: sp = s2; n = 128;  break;
    case 3: sp = s3; n = 1024; break;
    case 4: sp = s4; n = 1024; break;
    default: sp = s5; n = 256; break;
  }
  if (off < n)
    d[seg * 1024 + off] = f ? bf2f(((const ushort_t*)sp)[off]) : ((const float*)sp)[off];
}

// ||e_c||^2 from bf16 codebook. grid 4 x 256
__global__ void k_enorm(const ushort_t* __restrict__ embb, float* __restrict__ enorm){
  int c = blockIdx.x * blockDim.x + threadIdx.x;
  if (c < KCODES){
    float s = 0.f;
    for (int d = 0; d < LATENT; d++){ float v = bf2f(embb[c * LATENT + d]); s += v * v; }
    enorm[c] = s;
  }
}

// =====================================================================
// generic MFMA GEMM: C[M=32768,N] = A[M,K] @ Bt[N,K]^T (+bias) (+tanh)
// 128x128 tile / workgroup, 4 waves in 2x2, each 4x4 of 16x16x32 MFMAs.
//
// 1-D grid, size (N/128)*256. XCD-locality swizzle: XCD j = flat%8 owns
// m-tiles ≡ j (mod 8) and sweeps all n-blocks of one m-tile back-to-back,
// so the A-tile + whole B weight live in that XCD's 4 MB L2.
//
// LDS k-chunk XOR swizzle: global_load_lds pins LDS writes to lane order,
// so we swizzle which global k-chunk each lane fetches (c ^= (r>>1)&3) and
// XOR identically at fragment-read time -> ds_read_b128 2-way (free)
// instead of 8-way banked.
//
// MODE 0: out = bf16 activation buffer (TANH optional)
// MODE 1: z: fp32 buf + bf16 buf + d_out (flag dtype)
// MODE 2: recon: d_out only (flag dtype)
// MODE 3: VQ scores: acc - 0.5*enorm[col], per-row argmax -> candidates
// =====================================================================
template<int MODE, int TANH>
__global__ __launch_bounds__(256)
void k_gemm(const ushort_t* __restrict__ A, const ushort_t* __restrict__ Bt,
            const float* __restrict__ bias, int N, int K,
            ushort_t* __restrict__ outb, float* __restrict__ outf,
            void* __restrict__ dout, long dout_off,
            const float* __restrict__ enorm,
            float* __restrict__ cand_v, int* __restrict__ cand_i,
            const int* __restrict__ flagp)
{
  __shared__ __align__(16) ushort_t As[128 * 32];
  __shared__ __align__(16) ushort_t Bs[128 * 32];
  const int tid = threadIdx.x;
  const int w = tid >> 6, lane = tid & 63;
  const int lane15 = lane & 15, quad = lane >> 4;
  const int wr = w >> 1, wc = w & 1;

  // ---- XCD-locality block swizzle ----
  const int nx = N >> 7;                 // n-tiles (power of 2: 1,2,8)
  const int lnx = __builtin_ctz(nx);
  const int f = blockIdx.x;
  const int j8 = f & 7, s = f >> 3;
  const int n_idx = s & (nx - 1);
  const int m_idx = ((s >> lnx) << 3) | j8;
  const long m0 = (long)m_idx * 128;
  const int n0 = n_idx * 128;

  // staging: lane -> (row r = lane>>2, k-chunk c = lane&3), fetch chunk c^((r>>1)&3)
  const int lrow = lane >> 2;
  const int lk8  = (((lane & 3) ^ ((lane >> 3) & 3)) * 8);
  // fragment read slot swizzle (K-loop invariant)
  const int sw   = (lane15 >> 1) & 3;

  f32x4 acc[4][4];
  #pragma unroll
  for (int i = 0; i < 4; i++)
    #pragma unroll
    for (int j = 0; j < 4; j++) acc[i][j] = (f32x4){0.f, 0.f, 0.f, 0.f};

  const int nk = K >> 5;
  for (int kb = 0; kb < nk; kb++){
    const int k0 = kb << 5;
    __syncthreads();
    #pragma unroll
    for (int ss = 0; ss < 2; ss++){
      int m = w * 32 + ss * 16 + lrow;
      async16(A + ((m0 + m) * K + k0 + lk8), &As[(w * 32 + ss * 16) * 32]);
    }
    #pragma unroll
    for (int ss = 0; ss < 2; ss++){
      int n = w * 32 + ss * 16 + lrow;
      async16(Bt + ((long)(n0 + n) * K + k0 + lk8), &Bs[(w * 32 + ss * 16) * 32]);
    }
    __builtin_amdgcn_s_waitcnt(0);
    __syncthreads();

    bf16x8 af[4], bf[4];
    #pragma unroll
    for (int i = 0; i < 4; i++)
      af[i] = *(const bf16x8*)&As[(wr * 64 + i * 16 + lane15) * 32 + ((quad ^ sw) * 8)];
    #pragma unroll
    for (int j = 0; j < 4; j++)
      bf[j] = *(const bf16x8*)&Bs[(wc * 64 + j * 16 + lane15) * 32 + ((quad ^ sw) * 8)];
    #pragma unroll
    for (int i = 0; i < 4; i++)
      #pragma unroll
      for (int j = 0; j < 4; j++)
        acc[i][j] = __builtin_amdgcn_mfma_f32_16x16x32_bf16(af[i], bf[j], acc[i][j], 0, 0, 0);
  }

  // ---------------- epilogue ----------------
  if (MODE == 0){
    #pragma unroll
    for (int i = 0; i < 4; i++){
      int row_l = wr * 64 + i * 16 + quad * 4;
      #pragma unroll
      for (int j = 0; j < 4; j++){
        int col = n0 + wc * 64 + j * 16 + lane15;
        float b = bias[col];
        #pragma unroll
        for (int r = 0; r < 4; r++){
          float v = acc[i][j][r] + b;
          if (TANH) v = tanhf(v);
          outb[(m0 + row_l + r) * N + col] = f2bf(v);
        }
      }
    }
  } else if (MODE == 1){
    int fl = *flagp;
    #pragma unroll
    for (int i = 0; i < 4; i++){
      int row_l = wr * 64 + i * 16 + quad * 4;
      #pragma unroll
      for (int j = 0; j < 4; j++){
        int col = wc * 64 + j * 16 + lane15;   // N==128, n0==0
        float b = bias[col];
        #pragma unroll
        for (int r = 0; r < 4; r++){
          float v = acc[i][j][r] + b;
          long idx = (m0 + row_l + r) * 128 + col;
          outf[idx] = v;
          ushort_t bb = f2bf(v);
          outb[idx] = bb;
          if (fl) ((ushort_t*)dout)[dout_off + idx] = bb;
          else    ((float*)dout)[dout_off + idx] = v;
        }
      }
    }
  } else if (MODE == 2){
    int fl = *flagp;
    #pragma unroll
    for (int i = 0; i < 4; i++){
      int row_l = wr * 64 + i * 16 + quad * 4;
      #pragma unroll
      for (int j = 0; j < 4; j++){
        int col = n0 + wc * 64 + j * 16 + lane15;
        float b = bias[col];
        #pragma unroll
        for (int r = 0; r < 4; r++){
          float v = acc[i][j][r] + b;
          long idx = (m0 + row_l + r) * N + col;
          if (fl) ((ushort_t*)dout)[dout_off + idx] = f2bf(v);
          else    ((float*)dout)[dout_off + idx] = v;
        }
      }
    }
  } else { // MODE 3: VQ score + per-row argmax over this 128-col block
    float bestv[16]; int bestc[16];
    #pragma unroll
    for (int i = 0; i < 4; i++){
      #pragma unroll
      for (int r = 0; r < 4; r++){
        float best = -1e30f; int bcol = 0;
        #pragma unroll
        for (int j = 0; j < 4; j++){
          int col = n0 + wc * 64 + j * 16 + lane15;
          float v = acc[i][j][r] - 0.5f * enorm[col];
          if (v > best){ best = v; bcol = col; }
        }
        #pragma unroll
        for (int off = 1; off < 16; off <<= 1){
          float ov = __shfl_xor(best, off, 64);
          int   oc = __shfl_xor(bcol, off, 64);
          if (ov > best || (ov == best && oc < bcol)){ best = ov; bcol = oc; }
        }
        bestv[i * 4 + r] = best; bestc[i * 4 + r] = bcol;
      }
    }
    __syncthreads();                  // LDS free for reuse now
    float* lv = (float*)As;           // [128][2]
    int*   li = (int*)Bs;             // [128][2]
    #pragma unroll
    for (int i = 0; i < 4; i++)
      #pragma unroll
      for (int r = 0; r < 4; r++){
        int row_l = wr * 64 + i * 16 + quad * 4 + r;
        if (lane15 == 0){ lv[row_l * 2 + wc] = bestv[i * 4 + r]; li[row_l * 2 + wc] = bestc[i * 4 + r]; }
      }
    __syncthreads();
    if (tid < 128){
      float v0 = lv[tid * 2], v1 = lv[tid * 2 + 1];
      int   c0 = li[tid * 2], c1 = li[tid * 2 + 1];
      float bv; int bc;
      if (v1 > v0 || (v1 == v0 && c1 < c0)){ bv = v1; bc = c1; } else { bv = v0; bc = c0; }
      long row = m0 + tid;
      cand_v[row * 8 + n_idx] = bv;
      cand_i[row * 8 + n_idx] = bc;
    }
  }
}

// =====================================================================
// VQ finalize: per-row argmax over 8 candidates, gather code, emit
// quantized (decoder input, bf16), z_q to d_out, loss PARTIAL per block.
// grid 16384, block 256 (2 rows / block)
// =====================================================================
__global__ __launch_bounds__(256)
void k_vqfin(const float* __restrict__ cand_v, const int* __restrict__ cand_i,
             const float* __restrict__ zf, const ushort_t* __restrict__ embb,
             ushort_t* __restrict__ qb, void* __restrict__ dout, long zq_off,
             float* __restrict__ loss_part, const int* __restrict__ flagp)
{
  int f = *flagp;
  long row = (long)blockIdx.x * 2 + (threadIdx.x >> 7);
  int d = threadIdx.x & 127;
  float best = -1e30f; int bi = 0;
  #pragma unroll
  for (int nb = 0; nb < 8; nb++){
    float v = cand_v[row * 8 + nb]; int c = cand_i[row * 8 + nb];
    if (v > best || (v == best && c < bi)){ best = v; bi = c; }
  }
  ushort_t qbits = embb[(long)bi * LATENT + d];
  float q = bf2f(qbits);
  long idx = row * LATENT + d;
  qb[idx] = qbits;
  if (f) ((ushort_t*)dout)[zq_off + idx] = qbits;
  else   ((float*)dout)[zq_off + idx] = q;
  float diff = zf[idx] - q;
  float p = diff * diff;
  #pragma unroll
  for (int off = 32; off; off >>= 1) p += __shfl_down(p, off, 64);
  __shared__ float red[4];
  if ((threadIdx.x & 63) == 0) red[threadIdx.x >> 6] = p;
  __syncthreads();
  if (threadIdx.x == 0) loss_part[blockIdx.x] = red[0] + red[1] + red[2] + red[3];
}

// reduce 16384 partials -> final loss scalar. grid 1, block 256
__global__ __launch_bounds__(256)
void k_lossfin(const float* __restrict__ loss_part, void* __restrict__ dout,
               long off, const int* __restrict__ flagp){
  __shared__ float red[4];
  float s = 0.f;
  for (int i = threadIdx.x; i < BB / 2; i += 256) s += loss_part[i];
  #pragma unroll
  for (int o = 32; o; o >>= 1) s += __shfl_down(s, o, 64);
  if ((threadIdx.x & 63) == 0) red[threadIdx.x >> 6] = s;
  __syncthreads();
  if (threadIdx.x == 0){
    float v = 1.25f * (red[0] + red[1] + red[2] + red[3]) / (float)((long)BB * LATENT);
    if (*flagp) ((ushort_t*)dout)[off] = f2bf(v);
    else        ((float*)dout)[off] = v;
  }
}

// =====================================================================
extern "C" void kernel_launch(void* const* d_in, const int* in_sizes, int n_in,
                              void* d_out, int out_size, void* d_ws, size_t ws_size,
                              hipStream_t stream)
{
  (void)in_sizes; (void)n_in; (void)out_size; (void)ws_size;
  const void* action = d_in[1];
  const void* eW0 = d_in[2];  const void* eb0 = d_in[3];
  const void* eW1 = d_in[4];  const void* eb1 = d_in[5];
  const void* eW2 = d_in[6];  const void* eb2 = d_in[7];
  const void* emb = d_in[8];
  const void* dW0 = d_in[9];  const void* db0 = d_in[10];
  const void* dW1 = d_in[11]; const void* db1 = d_in[12];
  const void* dW2 = d_in[13]; const void* db2 = d_in[14];

  char* ws = (char*)d_ws;
  size_t off = 0;
  auto alloc = [&](size_t bytes)->char*{
    char* p = ws + off; off += bytes; off = (off + 255) & ~((size_t)255); return p;
  };
  int*      flag     = (int*)  alloc(4);
  float*    biasf    = (float*)alloc(6 * 1024 * 4);
  float*    enorm    = (float*)alloc(KCODES * 4);
  ushort_t* eW0t = (ushort_t*)alloc((size_t)HID * INDIM * 2);     // [1024][256]
  ushort_t* eW1t = (ushort_t*)alloc((size_t)HID * HID * 2);       // [1024][1024]
  ushort_t* eW2t = (ushort_t*)alloc((size_t)LATENT * HID * 2);    // [128][1024]
  ushort_t* embb = (ushort_t*)alloc((size_t)KCODES * LATENT * 2); // [1024][128]
  ushort_t* dW0t = (ushort_t*)alloc((size_t)HID * LATENT * 2);    // [1024][128]
  ushort_t* dW1t = (ushort_t*)alloc((size_t)HID * HID * 2);       // [1024][1024]
  ushort_t* dW2t = (ushort_t*)alloc((size_t)INDIM * HID * 2);     // [256][1024]
  ushort_t* act0 = (ushort_t*)alloc((size_t)BB * INDIM * 2);
  ushort_t* hA   = (ushort_t*)alloc((size_t)BB * HID * 2);
  ushort_t* hB   = (ushort_t*)alloc((size_t)BB * HID * 2);
  float*    zf32 = (float*)   alloc((size_t)BB * LATENT * 4);
  ushort_t* zb16 = (ushort_t*)alloc((size_t)BB * LATENT * 2);
  ushort_t* qb16 = (ushort_t*)alloc((size_t)BB * LATENT * 2);
  float*    cand_v = (float*) alloc((size_t)BB * 8 * 4);
  int*      cand_i = (int*)   alloc((size_t)BB * 8 * 4);
  float*    loss_part = (float*)alloc((size_t)(BB / 2) * 4);

  const long z_off  = (long)BB * INDIM;            // 8388608
  const long zq_off = z_off + (long)BB * LATENT;   // 12582912
  const long l_off  = zq_off + (long)BB * LATENT;  // 16777216

  // ---- prep ----
  k_sniff<<<1, 64, 0, stream>>>((const ushort_t*)action, flag);
  k_cvt<<<256, 256, 0, stream>>>(action, act0, BB * INDIM, flag);
  k_tcvt<<<dim3(HID / 32, INDIM / 32), 256, 0, stream>>>(eW0, eW0t, INDIM, HID, flag);
  k_tcvt<<<dim3(HID / 32, HID / 32),  256, 0, stream>>>(eW1, eW1t, HID, HID, flag);
  k_tcvt<<<dim3(LATENT / 32, HID / 32), 256, 0, stream>>>(eW2, eW2t, HID, LATENT, flag);
  k_tcvt<<<dim3(HID / 32, LATENT / 32), 256, 0, stream>>>(dW0, dW0t, LATENT, HID, flag);
  k_tcvt<<<dim3(HID / 32, HID / 32),  256, 0, stream>>>(dW1, dW1t, HID, HID, flag);
  k_tcvt<<<dim3(INDIM / 32, HID / 32), 256, 0, stream>>>(dW2, dW2t, HID, INDIM, flag);
  k_cvt<<<128, 256, 0, stream>>>(emb, embb, KCODES * LATENT, flag);
  k_bias<<<24, 256, 0, stream>>>(eb0, eb1, eb2, db0, db1, db2, biasf, flag);
  k_enorm<<<4, 256, 0, stream>>>(embb, enorm);

  // ---- encoder ----
  k_gemm<0, 1><<<8 * 256, 256, 0, stream>>>(act0, eW0t, biasf + 0, HID, INDIM,
      hA, nullptr, nullptr, 0, nullptr, nullptr, nullptr, flag);
  k_gemm<0, 1><<<8 * 256, 256, 0, stream>>>(hA, eW1t, biasf + 1024, HID, HID,
      hB, nullptr, nullptr, 0, nullptr, nullptr, nullptr, flag);
  k_gemm<1, 0><<<1 * 256, 256, 0, stream>>>(hB, eW2t, biasf + 2048, LATENT, HID,
      zb16, zf32, d_out, z_off, nullptr, nullptr, nullptr, flag);

  // ---- VQ ----
  k_gemm<3, 0><<<8 * 256, 256, 0, stream>>>(zb16, embb, nullptr, KCODES, LATENT,
      nullptr, nullptr, nullptr, 0, enorm, cand_v, cand_i, flag);
  k_vqfin<<<BB / 2, 256, 0, stream>>>(cand_v, cand_i, zf32, embb, qb16, d_out, zq_off,
      loss_part, flag);

  // ---- decoder ----
  k_gemm<0, 1><<<8 * 256, 256, 0, stream>>>(qb16, dW0t, biasf + 3072, HID, LATENT,
      hA, nullptr, nullptr, 0, nullptr, nullptr, nullptr, flag);
  k_gemm<0, 1><<<8 * 256, 256, 0, stream>>>(hA, dW1t, biasf + 4096, HID, HID,
      hB, nullptr, nullptr, 0, nullptr, nullptr, nullptr, flag);
  k_gemm<2, 0><<<2 * 256, 256, 0, stream>>>(hB, dW2t, biasf + 5120, INDIM, HID,
      nullptr, nullptr, d_out, 0, nullptr, nullptr, nullptr, flag);

  k_lossfin<<<1, 256, 0, stream>>>(loss_part, d_out, l_off, flag);
}

// Round 4
// 548.676 us; speedup vs baseline: 1.6279x; 1.2368x over previous
//
#include <hip/hip_runtime.h>
#include <stdint.h>
#include <math.h>

#define DEVI __device__ __forceinline__
typedef unsigned short ushort_t;
typedef __attribute__((ext_vector_type(8))) __bf16 bf16x8;
typedef __attribute__((ext_vector_type(4))) float f32x4;

// ---------- scalar bf16 helpers (RNE, matches HW/harness encoding) ----------
DEVI float bf2f(ushort_t b){ union{uint32_t u; float f;} c; c.u = ((uint32_t)b) << 16; return c.f; }
DEVI ushort_t f2bf(float f){ union{float f; uint32_t u;} c; c.f = f; uint32_t u = c.u;
                             u += 0x7fffu + ((u >> 16) & 1u); return (ushort_t)(u >> 16); }

// fast tanh: 1 - 2/(exp2(2*log2e*x)+1). v_exp_f32+v_rcp_f32, ~5 VALU ops vs
// ~30 for libm tanhf (the R3 epilogue VALU hog). Saturates correctly at +-inf.
DEVI float fast_tanh(float x){
  float t = __builtin_amdgcn_exp2f(x * 2.8853900817779268f);
  return 1.0f - 2.0f * __builtin_amdgcn_rcpf(t + 1.0f);
}

// ---------- async global->LDS (16B per lane, dest = wave-uniform base + lane*16) ----------
DEVI void async16(const ushort_t* g, ushort_t* l){
  __builtin_amdgcn_global_load_lds((const __attribute__((address_space(1))) void*)g,
                                   (__attribute__((address_space(3))) void*)l, 16, 0, 0);
}

// ---------- problem constants ----------
#define BB 32768
#define INDIM 256
#define LATENT 128
#define HID 1024
#define KCODES 1024

// =====================================================================
// dtype sniffer: flag = 1 -> buffers are bf16 ; flag = 0 -> fp32
// =====================================================================
__global__ void k_sniff(const ushort_t* __restrict__ act, int* flag){
  if (threadIdx.x == 0){
    int bad = 0;
    for (int i = 0; i < 256; i++){
      float v = bf2f(act[i]);
      float a = fabsf(v);
      if (!(a <= 16.0f) || (a > 0.0f && a < 9.5e-7f)) bad++;
    }
    flag[0] = (bad >= 8) ? 0 : 1;
  }
}

// convert (no transpose) to bf16 bits, 8 elements / thread (16B stores)
__global__ void k_cvt(const void* __restrict__ src, ushort_t* __restrict__ dst, int n8,
                      const int* __restrict__ flagp){
  int f = *flagp;
  int i = blockIdx.x * blockDim.x + threadIdx.x;
  if (i >= n8) return;
  if (f){
    ((uint4*)dst)[i] = ((const uint4*)src)[i];
  } else {
    const float* s = (const float*)src + (size_t)i * 8;
    ushort_t o[8];
    #pragma unroll
    for (int j = 0; j < 8; j++) o[j] = f2bf(s[j]);
    ((uint4*)dst)[i] = *(const uint4*)o;
  }
}

// convert + transpose: src[R][C] -> dst[C][R] (bf16). grid(C/32, R/32), block 256
__global__ void k_tcvt(const void* __restrict__ src, ushort_t* __restrict__ dst, int R, int C,
                       const int* __restrict__ flagp){
  __shared__ ushort_t tile[32][33];
  int f = *flagp;
  int tx = threadIdx.x & 31, ty = threadIdx.x >> 5;
  int c = blockIdx.x * 32 + tx;
  #pragma unroll
  for (int ii = 0; ii < 4; ii++){
    int r = blockIdx.y * 32 + ty + ii * 8;
    long idx = (long)r * C + c;
    tile[ty + ii * 8][tx] = f ? ((const ushort_t*)src)[idx] : f2bf(((const float*)src)[idx]);
  }
  __syncthreads();
  #pragma unroll
  for (int ii = 0; ii < 4; ii++){
    int cc = blockIdx.x * 32 + ty + ii * 8;
    dst[(long)cc * R + blockIdx.y * 32 + tx] = tile[tx][ty + ii * 8];
  }
}

// all 6 biases -> fp32, 1024-float slots. grid 24 x 256
__global__ void k_bias(const void* s0, const void* s1, const void* s2,
                       const void* s3, const void* s4, const void* s5,
                       float* __restrict__ d, const int* __restrict__ flagp){
  int f = *flagp;
  int i = blockIdx.x * blockDim.x + threadIdx.x;
  int seg = i >> 10, off = i & 1023;
  const void* sp; int n;
  switch (seg){
    case 0: sp = s0; n = 1024; break;
    case 1: sp = s1; n = 1024; break;
    case 2: sp = s2; n = 128;  break;
    case 3: sp = s3; n = 1024; break;
    case 4: sp = s4; n = 1024; break;
    default: sp = s5; n = 256; break;
  }
  if (off < n)
    d[seg * 1024 + off] = f ? bf2f(((const ushort_t*)sp)[off]) : ((const float*)sp)[off];
}

// ||e_c||^2 from bf16 codebook. grid 4 x 256
__global__ void k_enorm(const ushort_t* __restrict__ embb, float* __restrict__ enorm){
  int c = blockIdx.x * blockDim.x + threadIdx.x;
  if (c < KCODES){
    float s = 0.f;
    for (int d = 0; d < LATENT; d++){ float v = bf2f(embb[c * LATENT + d]); s += v * v; }
    enorm[c] = s;
  }
}

// =====================================================================
// generic MFMA GEMM: C[M=32768,N] = A[M,K] @ Bt[N,K]^T (+bias) (+tanh)
// 128x128 tile / workgroup, 4 waves in 2x2, each 4x4 of 16x16x32 MFMAs.
// 1-D grid with XCD-locality swizzle (R3: FETCH 265->57 MB).
// k-chunk XOR swizzle keeps ds_read_b128 2-way conflict-free (R3: 8.4M->0).
//
// MODE 0: out = bf16 activation buffer (TANH optional)
// MODE 1: z: fp32 buf + bf16 buf + d_out (flag dtype)
// MODE 2: recon: d_out only (flag dtype)
// MODE 3: VQ scores: acc - 0.5*enorm[col], per-row argmax -> candidates
// =====================================================================
template<int MODE, int TANH>
__global__ __launch_bounds__(256)
void k_gemm(const ushort_t* __restrict__ A, const ushort_t* __restrict__ Bt,
            const float* __restrict__ bias, int N, int K,
            ushort_t* __restrict__ outb, float* __restrict__ outf,
            void* __restrict__ dout, long dout_off,
            const float* __restrict__ enorm,
            float* __restrict__ cand_v, int* __restrict__ cand_i,
            const int* __restrict__ flagp)
{
  __shared__ __align__(16) ushort_t As[128 * 32];
  __shared__ __align__(16) ushort_t Bs[128 * 32];
  const int tid = threadIdx.x;
  const int w = tid >> 6, lane = tid & 63;
  const int lane15 = lane & 15, quad = lane >> 4;
  const int wr = w >> 1, wc = w & 1;

  // ---- XCD-locality block swizzle ----
  const int nx = N >> 7;                 // n-tiles (power of 2: 1,2,8)
  const int lnx = __builtin_ctz(nx);
  const int f = blockIdx.x;
  const int j8 = f & 7, s = f >> 3;
  const int n_idx = s & (nx - 1);
  const int m_idx = ((s >> lnx) << 3) | j8;
  const long m0 = (long)m_idx * 128;
  const int n0 = n_idx * 128;

  // staging: lane -> (row r = lane>>2, k-chunk c = lane&3), fetch chunk c^((r>>1)&3)
  const int lrow = lane >> 2;
  const int lk8  = (((lane & 3) ^ ((lane >> 3) & 3)) * 8);
  // fragment read slot swizzle (K-loop invariant)
  const int sw   = (lane15 >> 1) & 3;

  f32x4 acc[4][4];
  #pragma unroll
  for (int i = 0; i < 4; i++)
    #pragma unroll
    for (int j = 0; j < 4; j++) acc[i][j] = (f32x4){0.f, 0.f, 0.f, 0.f};

  const int nk = K >> 5;
  for (int kb = 0; kb < nk; kb++){
    const int k0 = kb << 5;
    __syncthreads();
    #pragma unroll
    for (int ss = 0; ss < 2; ss++){
      int m = w * 32 + ss * 16 + lrow;
      async16(A + ((m0 + m) * K + k0 + lk8), &As[(w * 32 + ss * 16) * 32]);
    }
    #pragma unroll
    for (int ss = 0; ss < 2; ss++){
      int n = w * 32 + ss * 16 + lrow;
      async16(Bt + ((long)(n0 + n) * K + k0 + lk8), &Bs[(w * 32 + ss * 16) * 32]);
    }
    __builtin_amdgcn_s_waitcnt(0);
    __syncthreads();

    bf16x8 af[4], bf[4];
    #pragma unroll
    for (int i = 0; i < 4; i++)
      af[i] = *(const bf16x8*)&As[(wr * 64 + i * 16 + lane15) * 32 + ((quad ^ sw) * 8)];
    #pragma unroll
    for (int j = 0; j < 4; j++)
      bf[j] = *(const bf16x8*)&Bs[(wc * 64 + j * 16 + lane15) * 32 + ((quad ^ sw) * 8)];
    #pragma unroll
    for (int i = 0; i < 4; i++)
      #pragma unroll
      for (int j = 0; j < 4; j++)
        acc[i][j] = __builtin_amdgcn_mfma_f32_16x16x32_bf16(af[i], bf[j], acc[i][j], 0, 0, 0);
  }

  // ---------------- epilogue ----------------
  if (MODE == 0){
    #pragma unroll
    for (int i = 0; i < 4; i++){
      int row_l = wr * 64 + i * 16 + quad * 4;
      #pragma unroll
      for (int j = 0; j < 4; j++){
        int col = n0 + wc * 64 + j * 16 + lane15;
        float b = bias[col];
        #pragma unroll
        for (int r = 0; r < 4; r++){
          float v = acc[i][j][r] + b;
          if (TANH) v = fast_tanh(v);
          outb[(m0 + row_l + r) * N + col] = f2bf(v);
        }
      }
    }
  } else if (MODE == 1){
    int fl = *flagp;
    #pragma unroll
    for (int i = 0; i < 4; i++){
      int row_l = wr * 64 + i * 16 + quad * 4;
      #pragma unroll
      for (int j = 0; j < 4; j++){
        int col = wc * 64 + j * 16 + lane15;   // N==128, n0==0
        float b = bias[col];
        #pragma unroll
        for (int r = 0; r < 4; r++){
          float v = acc[i][j][r] + b;
          long idx = (m0 + row_l + r) * 128 + col;
          outf[idx] = v;
          ushort_t bb = f2bf(v);
          outb[idx] = bb;
          if (fl) ((ushort_t*)dout)[dout_off + idx] = bb;
          else    ((float*)dout)[dout_off + idx] = v;
        }
      }
    }
  } else if (MODE == 2){
    int fl = *flagp;
    #pragma unroll
    for (int i = 0; i < 4; i++){
      int row_l = wr * 64 + i * 16 + quad * 4;
      #pragma unroll
      for (int j = 0; j < 4; j++){
        int col = n0 + wc * 64 + j * 16 + lane15;
        float b = bias[col];
        #pragma unroll
        for (int r = 0; r < 4; r++){
          float v = acc[i][j][r] + b;
          long idx = (m0 + row_l + r) * N + col;
          if (fl) ((ushort_t*)dout)[dout_off + idx] = f2bf(v);
          else    ((float*)dout)[dout_off + idx] = v;
        }
      }
    }
  } else { // MODE 3: VQ score + per-row argmax over this 128-col block
    float bestv[16]; int bestc[16];
    #pragma unroll
    for (int i = 0; i < 4; i++){
      #pragma unroll
      for (int r = 0; r < 4; r++){
        float best = -1e30f; int bcol = 0;
        #pragma unroll
        for (int j = 0; j < 4; j++){
          int col = n0 + wc * 64 + j * 16 + lane15;
          float v = acc[i][j][r] - 0.5f * enorm[col];
          if (v > best){ best = v; bcol = col; }
        }
        #pragma unroll
        for (int off = 1; off < 16; off <<= 1){
          float ov = __shfl_xor(best, off, 64);
          int   oc = __shfl_xor(bcol, off, 64);
          if (ov > best || (ov == best && oc < bcol)){ best = ov; bcol = oc; }
        }
        bestv[i * 4 + r] = best; bestc[i * 4 + r] = bcol;
      }
    }
    __syncthreads();                  // LDS free for reuse now
    float* lv = (float*)As;           // [128][2]
    int*   li = (int*)Bs;             // [128][2]
    #pragma unroll
    for (int i = 0; i < 4; i++)
      #pragma unroll
      for (int r = 0; r < 4; r++){
        int row_l = wr * 64 + i * 16 + quad * 4 + r;
        if (lane15 == 0){ lv[row_l * 2 + wc] = bestv[i * 4 + r]; li[row_l * 2 + wc] = bestc[i * 4 + r]; }
      }
    __syncthreads();
    if (tid < 128){
      float v0 = lv[tid * 2], v1 = lv[tid * 2 + 1];
      int   c0 = li[tid * 2], c1 = li[tid * 2 + 1];
      float bv; int bc;
      if (v1 > v0 || (v1 == v0 && c1 < c0)){ bv = v1; bc = c1; } else { bv = v0; bc = c0; }
      long row = m0 + tid;
      cand_v[row * 8 + n_idx] = bv;
      cand_i[row * 8 + n_idx] = bc;
    }
  }
}

// =====================================================================
// VQ finalize: per-row argmax over 8 candidates, gather code, emit
// quantized (decoder input, bf16), z_q to d_out, loss PARTIAL per block.
// grid 16384, block 256 (2 rows / block)
// =====================================================================
__global__ __launch_bounds__(256)
void k_vqfin(const float* __restrict__ cand_v, const int* __restrict__ cand_i,
             const float* __restrict__ zf, const ushort_t* __restrict__ embb,
             ushort_t* __restrict__ qb, void* __restrict__ dout, long zq_off,
             float* __restrict__ loss_part, const int* __restrict__ flagp)
{
  int f = *flagp;
  long row = (long)blockIdx.x * 2 + (threadIdx.x >> 7);
  int d = threadIdx.x & 127;
  float best = -1e30f; int bi = 0;
  #pragma unroll
  for (int nb = 0; nb < 8; nb++){
    float v = cand_v[row * 8 + nb]; int c = cand_i[row * 8 + nb];
    if (v > best || (v == best && c < bi)){ best = v; bi = c; }
  }
  ushort_t qbits = embb[(long)bi * LATENT + d];
  float q = bf2f(qbits);
  long idx = row * LATENT + d;
  qb[idx] = qbits;
  if (f) ((ushort_t*)dout)[zq_off + idx] = qbits;
  else   ((float*)dout)[zq_off + idx] = q;
  float diff = zf[idx] - q;
  float p = diff * diff;
  #pragma unroll
  for (int off = 32; off; off >>= 1) p += __shfl_down(p, off, 64);
  __shared__ float red[4];
  if ((threadIdx.x & 63) == 0) red[threadIdx.x >> 6] = p;
  __syncthreads();
  if (threadIdx.x == 0) loss_part[blockIdx.x] = red[0] + red[1] + red[2] + red[3];
}

// reduce 16384 partials -> final loss scalar. grid 1, block 256
__global__ __launch_bounds__(256)
void k_lossfin(const float* __restrict__ loss_part, void* __restrict__ dout,
               long off, const int* __restrict__ flagp){
  __shared__ float red[4];
  float s = 0.f;
  for (int i = threadIdx.x; i < BB / 2; i += 256) s += loss_part[i];
  #pragma unroll
  for (int o = 32; o; o >>= 1) s += __shfl_down(s, o, 64);
  if ((threadIdx.x & 63) == 0) red[threadIdx.x >> 6] = s;
  __syncthreads();
  if (threadIdx.x == 0){
    float v = 1.25f * (red[0] + red[1] + red[2] + red[3]) / (float)((long)BB * LATENT);
    if (*flagp) ((ushort_t*)dout)[off] = f2bf(v);
    else        ((float*)dout)[off] = v;
  }
}

// =====================================================================
extern "C" void kernel_launch(void* const* d_in, const int* in_sizes, int n_in,
                              void* d_out, int out_size, void* d_ws, size_t ws_size,
                              hipStream_t stream)
{
  (void)in_sizes; (void)n_in; (void)out_size; (void)ws_size;
  const void* action = d_in[1];
  const void* eW0 = d_in[2];  const void* eb0 = d_in[3];
  const void* eW1 = d_in[4];  const void* eb1 = d_in[5];
  const void* eW2 = d_in[6];  const void* eb2 = d_in[7];
  const void* emb = d_in[8];
  const void* dW0 = d_in[9];  const void* db0 = d_in[10];
  const void* dW1 = d_in[11]; const void* db1 = d_in[12];
  const void* dW2 = d_in[13]; const void* db2 = d_in[14];

  char* ws = (char*)d_ws;
  size_t off = 0;
  auto alloc = [&](size_t bytes)->char*{
    char* p = ws + off; off += bytes; off = (off + 255) & ~((size_t)255); return p;
  };
  int*      flag     = (int*)  alloc(4);
  float*    biasf    = (float*)alloc(6 * 1024 * 4);
  float*    enorm    = (float*)alloc(KCODES * 4);
  ushort_t* eW0t = (ushort_t*)alloc((size_t)HID * INDIM * 2);     // [1024][256]
  ushort_t* eW1t = (ushort_t*)alloc((size_t)HID * HID * 2);       // [1024][1024]
  ushort_t* eW2t = (ushort_t*)alloc((size_t)LATENT * HID * 2);    // [128][1024]
  ushort_t* embb = (ushort_t*)alloc((size_t)KCODES * LATENT * 2); // [1024][128]
  ushort_t* dW0t = (ushort_t*)alloc((size_t)HID * LATENT * 2);    // [1024][128]
  ushort_t* dW1t = (ushort_t*)alloc((size_t)HID * HID * 2);       // [1024][1024]
  ushort_t* dW2t = (ushort_t*)alloc((size_t)INDIM * HID * 2);     // [256][1024]
  ushort_t* act0 = (ushort_t*)alloc((size_t)BB * INDIM * 2);
  ushort_t* hA   = (ushort_t*)alloc((size_t)BB * HID * 2);
  ushort_t* hB   = (ushort_t*)alloc((size_t)BB * HID * 2);
  float*    zf32 = (float*)   alloc((size_t)BB * LATENT * 4);
  ushort_t* zb16 = (ushort_t*)alloc((size_t)BB * LATENT * 2);
  ushort_t* qb16 = (ushort_t*)alloc((size_t)BB * LATENT * 2);
  float*    cand_v = (float*) alloc((size_t)BB * 8 * 4);
  int*      cand_i = (int*)   alloc((size_t)BB * 8 * 4);
  float*    loss_part = (float*)alloc((size_t)(BB / 2) * 4);

  const long z_off  = (long)BB * INDIM;            // 8388608
  const long zq_off = z_off + (long)BB * LATENT;   // 12582912
  const long l_off  = zq_off + (long)BB * LATENT;  // 16777216

  // ---- prep ----
  k_sniff<<<1, 64, 0, stream>>>((const ushort_t*)action, flag);
  k_cvt<<<(BB * INDIM / 8 + 255) / 256, 256, 0, stream>>>(action, act0, BB * INDIM / 8, flag);
  k_tcvt<<<dim3(HID / 32, INDIM / 32), 256, 0, stream>>>(eW0, eW0t, INDIM, HID, flag);
  k_tcvt<<<dim3(HID / 32, HID / 32),  256, 0, stream>>>(eW1, eW1t, HID, HID, flag);
  k_tcvt<<<dim3(LATENT / 32, HID / 32), 256, 0, stream>>>(eW2, eW2t, HID, LATENT, flag);
  k_tcvt<<<dim3(HID / 32, LATENT / 32), 256, 0, stream>>>(dW0, dW0t, LATENT, HID, flag);
  k_tcvt<<<dim3(HID / 32, HID / 32),  256, 0, stream>>>(dW1, dW1t, HID, HID, flag);
  k_tcvt<<<dim3(INDIM / 32, HID / 32), 256, 0, stream>>>(dW2, dW2t, HID, INDIM, flag);
  k_cvt<<<(KCODES * LATENT / 8 + 255) / 256, 256, 0, stream>>>(emb, embb, KCODES * LATENT / 8, flag);
  k_bias<<<24, 256, 0, stream>>>(eb0, eb1, eb2, db0, db1, db2, biasf, flag);
  k_enorm<<<4, 256, 0, stream>>>(embb, enorm);

  // ---- encoder ----
  k_gemm<0, 1><<<8 * 256, 256, 0, stream>>>(act0, eW0t, biasf + 0, HID, INDIM,
      hA, nullptr, nullptr, 0, nullptr, nullptr, nullptr, flag);
  k_gemm<0, 1><<<8 * 256, 256, 0, stream>>>(hA, eW1t, biasf + 1024, HID, HID,
      hB, nullptr, nullptr, 0, nullptr, nullptr, nullptr, flag);
  k_gemm<1, 0><<<1 * 256, 256, 0, stream>>>(hB, eW2t, biasf + 2048, LATENT, HID,
      zb16, zf32, d_out, z_off, nullptr, nullptr, nullptr, flag);

  // ---- VQ ----
  k_gemm<3, 0><<<8 * 256, 256, 0, stream>>>(zb16, embb, nullptr, KCODES, LATENT,
      nullptr, nullptr, nullptr, 0, enorm, cand_v, cand_i, flag);
  k_vqfin<<<BB / 2, 256, 0, stream>>>(cand_v, cand_i, zf32, embb, qb16, d_out, zq_off,
      loss_part, flag);

  // ---- decoder ----
  k_gemm<0, 1><<<8 * 256, 256, 0, stream>>>(qb16, dW0t, biasf + 3072, HID, LATENT,
      hA, nullptr, nullptr, 0, nullptr, nullptr, nullptr, flag);
  k_gemm<0, 1><<<8 * 256, 256, 0, stream>>>(hA, dW1t, biasf + 4096, HID, HID,
      hB, nullptr, nullptr, 0, nullptr, nullptr, nullptr, flag);
  k_gemm<2, 0><<<2 * 256, 256, 0, stream>>>(hB, dW2t, biasf + 5120, INDIM, HID,
      nullptr, nullptr, d_out, 0, nullptr, nullptr, nullptr, flag);

  k_lossfin<<<1, 256, 0, stream>>>(loss_part, d_out, l_off, flag);
}

// Round 5
// 531.007 us; speedup vs baseline: 1.6820x; 1.0333x over previous
//
#include <hip/hip_runtime.h>
#include <stdint.h>
#include <math.h>

#define DEVI __device__ __forceinline__
typedef unsigned short ushort_t;
typedef __attribute__((ext_vector_type(8))) __bf16 bf16x8;
typedef __attribute__((ext_vector_type(4))) float f32x4;

// ---------- scalar bf16 helpers (RNE, matches HW/harness encoding) ----------
DEVI float bf2f(ushort_t b){ union{uint32_t u; float f;} c; c.u = ((uint32_t)b) << 16; return c.f; }
DEVI ushort_t f2bf(float f){ union{float f; uint32_t u;} c; c.f = f; uint32_t u = c.u;
                             u += 0x7fffu + ((u >> 16) & 1u); return (ushort_t)(u >> 16); }

// fast tanh: 1 - 2/(exp2(2*log2e*x)+1). ~5 VALU ops, saturates correctly.
DEVI float fast_tanh(float x){
  float t = __builtin_amdgcn_exp2f(x * 2.8853900817779268f);
  return 1.0f - 2.0f * __builtin_amdgcn_rcpf(t + 1.0f);
}

// ---------- async global->LDS (16B per lane, dest = wave-uniform base + lane*16) ----------
DEVI void async16(const ushort_t* g, ushort_t* l){
  __builtin_amdgcn_global_load_lds((const __attribute__((address_space(1))) void*)g,
                                   (__attribute__((address_space(3))) void*)l, 16, 0, 0);
}

// ---------- problem constants ----------
#define BB 32768
#define INDIM 256
#define LATENT 128
#define HID 1024
#define KCODES 1024

// =====================================================================
// dtype sniffer: flag = 1 -> buffers are bf16 ; flag = 0 -> fp32
// =====================================================================
__global__ void k_sniff(const ushort_t* __restrict__ act, int* flag){
  if (threadIdx.x == 0){
    int bad = 0;
    for (int i = 0; i < 256; i++){
      float v = bf2f(act[i]);
      float a = fabsf(v);
      if (!(a <= 16.0f) || (a > 0.0f && a < 9.5e-7f)) bad++;
    }
    flag[0] = (bad >= 8) ? 0 : 1;
  }
}

// convert (no transpose) to bf16 bits, 8 elements / thread (16B stores)
__global__ void k_cvt(const void* __restrict__ src, ushort_t* __restrict__ dst, int n8,
                      const int* __restrict__ flagp){
  int f = *flagp;
  int i = blockIdx.x * blockDim.x + threadIdx.x;
  if (i >= n8) return;
  if (f){
    ((uint4*)dst)[i] = ((const uint4*)src)[i];
  } else {
    const float* s = (const float*)src + (size_t)i * 8;
    ushort_t o[8];
    #pragma unroll
    for (int j = 0; j < 8; j++) o[j] = f2bf(s[j]);
    ((uint4*)dst)[i] = *(const uint4*)o;
  }
}

// convert + transpose: src[R][C] -> dst[C][R] (bf16). grid(C/32, R/32), block 256
__global__ void k_tcvt(const void* __restrict__ src, ushort_t* __restrict__ dst, int R, int C,
                       const int* __restrict__ flagp){
  __shared__ ushort_t tile[32][33];
  int f = *flagp;
  int tx = threadIdx.x & 31, ty = threadIdx.x >> 5;
  int c = blockIdx.x * 32 + tx;
  #pragma unroll
  for (int ii = 0; ii < 4; ii++){
    int r = blockIdx.y * 32 + ty + ii * 8;
    long idx = (long)r * C + c;
    tile[ty + ii * 8][tx] = f ? ((const ushort_t*)src)[idx] : f2bf(((const float*)src)[idx]);
  }
  __syncthreads();
  #pragma unroll
  for (int ii = 0; ii < 4; ii++){
    int cc = blockIdx.x * 32 + ty + ii * 8;
    dst[(long)cc * R + blockIdx.y * 32 + tx] = tile[tx][ty + ii * 8];
  }
}

// all 6 biases -> fp32, 1024-float slots. grid 24 x 256
__global__ void k_bias(const void* s0, const void* s1, const void* s2,
                       const void* s3, const void* s4, const void* s5,
                       float* __restrict__ d, const int* __restrict__ flagp){
  int f = *flagp;
  int i = blockIdx.x * blockDim.x + threadIdx.x;
  int seg = i >> 10, off = i & 1023;
  const void* sp; int n;
  switch (seg){
    case 0: sp = s0; n = 1024; break;
    case 1: sp = s1; n = 1024; break;
    case 2: sp = s2; n = 128;  break;
    case 3: sp = s3; n = 1024; break;
    case 4: sp = s4; n = 1024; break;
    default: sp = s5; n = 256; break;
  }
  if (off < n)
    d[seg * 1024 + off] = f ? bf2f(((const ushort_t*)sp)[off]) : ((const float*)sp)[off];
}

// ||e_c||^2 from bf16 codebook. grid 4 x 256
__global__ void k_enorm(const ushort_t* __restrict__ embb, float* __restrict__ enorm){
  int c = blockIdx.x * blockDim.x + threadIdx.x;
  if (c < KCODES){
    float s = 0.f;
    for (int d = 0; d < LATENT; d++){ float v = bf2f(embb[c * LATENT + d]); s += v * v; }
    enorm[c] = s;
  }
}

// =====================================================================
// WIDE MFMA GEMM (N==1024 activations): C = tanh(A[M,K] @ Bt[N,K]^T + b)
// 128x256 block tile, 4 waves in 2x2, wave tile 64x128 (4x8 of 16x16x32).
// vs the 128x128 kernel: staging bytes/MFMA -25%, ds_read bytes/MFMA -25%,
// barriers/MFMA halved — attacks the R4 structure-bound 25.5% MfmaUtil.
// Same XCD swizzle + k-chunk XOR (both verified: FETCH 265->57MB, conflicts 0).
// =====================================================================
__global__ __launch_bounds__(256, 2)
void k_gemmw(const ushort_t* __restrict__ A, const ushort_t* __restrict__ Bt,
             const float* __restrict__ bias, int K,
             ushort_t* __restrict__ outb)
{
  const int N = 1024;
  __shared__ __align__(16) ushort_t As[128 * 32];   //  8 KB
  __shared__ __align__(16) ushort_t Bs[256 * 32];   // 16 KB
  const int tid = threadIdx.x;
  const int w = tid >> 6, lane = tid & 63;
  const int lane15 = lane & 15, quad = lane >> 4;
  const int wr = w >> 1, wc = w & 1;

  // ---- XCD-locality swizzle: 4 n-tiles (256 wide), 256 m-tiles ----
  const int f = blockIdx.x;
  const int j8 = f & 7, s = f >> 3;
  const int n_idx = s & 3;
  const int m_idx = ((s >> 2) << 3) | j8;
  const long m0 = (long)m_idx * 128;
  const int n0 = n_idx * 256;

  const int lrow = lane >> 2;
  const int lk8  = (((lane & 3) ^ ((lane >> 3) & 3)) * 8);
  const int sw   = (lane15 >> 1) & 3;

  f32x4 acc[4][8];
  #pragma unroll
  for (int i = 0; i < 4; i++)
    #pragma unroll
    for (int j = 0; j < 8; j++) acc[i][j] = (f32x4){0.f, 0.f, 0.f, 0.f};

  const int nk = K >> 5;
  for (int kb = 0; kb < nk; kb++){
    const int k0 = kb << 5;
    __syncthreads();
    #pragma unroll
    for (int a = 0; a < 2; a++){
      int m = w * 32 + a * 16 + lrow;
      async16(A + ((m0 + m) * K + k0 + lk8), &As[(w * 32 + a * 16) * 32]);
    }
    #pragma unroll
    for (int b = 0; b < 4; b++){
      int n = w * 64 + b * 16 + lrow;
      async16(Bt + ((long)(n0 + n) * K + k0 + lk8), &Bs[(w * 64 + b * 16) * 32]);
    }
    __builtin_amdgcn_s_waitcnt(0);
    __syncthreads();

    bf16x8 af[4], bf[8];
    #pragma unroll
    for (int i = 0; i < 4; i++)
      af[i] = *(const bf16x8*)&As[(wr * 64 + i * 16 + lane15) * 32 + ((quad ^ sw) * 8)];
    #pragma unroll
    for (int j = 0; j < 8; j++)
      bf[j] = *(const bf16x8*)&Bs[(wc * 128 + j * 16 + lane15) * 32 + ((quad ^ sw) * 8)];
    #pragma unroll
    for (int i = 0; i < 4; i++)
      #pragma unroll
      for (int j = 0; j < 8; j++)
        acc[i][j] = __builtin_amdgcn_mfma_f32_16x16x32_bf16(af[i], bf[j], acc[i][j], 0, 0, 0);
  }

  #pragma unroll
  for (int i = 0; i < 4; i++){
    int row_l = wr * 64 + i * 16 + quad * 4;
    #pragma unroll
    for (int j = 0; j < 8; j++){
      int col = n0 + wc * 128 + j * 16 + lane15;
      float b = bias[col];
      #pragma unroll
      for (int r = 0; r < 4; r++){
        float v = fast_tanh(acc[i][j][r] + b);
        outb[(m0 + row_l + r) * N + col] = f2bf(v);
      }
    }
  }
}

// =====================================================================
// generic 128x128 MFMA GEMM (z / VQ / dec-L2 shapes).
// MODE 1: z: fp32 buf + bf16 buf + d_out (flag dtype)      [N=128]
// MODE 2: recon: d_out only (flag dtype)                   [N=256]
// MODE 3: VQ scores: acc - 0.5*enorm[col], per-row argmax  [N=1024]
// =====================================================================
template<int MODE>
__global__ __launch_bounds__(256)
void k_gemm(const ushort_t* __restrict__ A, const ushort_t* __restrict__ Bt,
            const float* __restrict__ bias, int N, int K,
            ushort_t* __restrict__ outb, float* __restrict__ outf,
            void* __restrict__ dout, long dout_off,
            const float* __restrict__ enorm,
            float* __restrict__ cand_v, int* __restrict__ cand_i,
            const int* __restrict__ flagp)
{
  __shared__ __align__(16) ushort_t As[128 * 32];
  __shared__ __align__(16) ushort_t Bs[128 * 32];
  const int tid = threadIdx.x;
  const int w = tid >> 6, lane = tid & 63;
  const int lane15 = lane & 15, quad = lane >> 4;
  const int wr = w >> 1, wc = w & 1;

  const int nx = N >> 7;
  const int lnx = __builtin_ctz(nx);
  const int f = blockIdx.x;
  const int j8 = f & 7, s = f >> 3;
  const int n_idx = s & (nx - 1);
  const int m_idx = ((s >> lnx) << 3) | j8;
  const long m0 = (long)m_idx * 128;
  const int n0 = n_idx * 128;

  const int lrow = lane >> 2;
  const int lk8  = (((lane & 3) ^ ((lane >> 3) & 3)) * 8);
  const int sw   = (lane15 >> 1) & 3;

  f32x4 acc[4][4];
  #pragma unroll
  for (int i = 0; i < 4; i++)
    #pragma unroll
    for (int j = 0; j < 4; j++) acc[i][j] = (f32x4){0.f, 0.f, 0.f, 0.f};

  const int nk = K >> 5;
  for (int kb = 0; kb < nk; kb++){
    const int k0 = kb << 5;
    __syncthreads();
    #pragma unroll
    for (int ss = 0; ss < 2; ss++){
      int m = w * 32 + ss * 16 + lrow;
      async16(A + ((m0 + m) * K + k0 + lk8), &As[(w * 32 + ss * 16) * 32]);
    }
    #pragma unroll
    for (int ss = 0; ss < 2; ss++){
      int n = w * 32 + ss * 16 + lrow;
      async16(Bt + ((long)(n0 + n) * K + k0 + lk8), &Bs[(w * 32 + ss * 16) * 32]);
    }
    __builtin_amdgcn_s_waitcnt(0);
    __syncthreads();

    bf16x8 af[4], bf[4];
    #pragma unroll
    for (int i = 0; i < 4; i++)
      af[i] = *(const bf16x8*)&As[(wr * 64 + i * 16 + lane15) * 32 + ((quad ^ sw) * 8)];
    #pragma unroll
    for (int j = 0; j < 4; j++)
      bf[j] = *(const bf16x8*)&Bs[(wc * 64 + j * 16 + lane15) * 32 + ((quad ^ sw) * 8)];
    #pragma unroll
    for (int i = 0; i < 4; i++)
      #pragma unroll
      for (int j = 0; j < 4; j++)
        acc[i][j] = __builtin_amdgcn_mfma_f32_16x16x32_bf16(af[i], bf[j], acc[i][j], 0, 0, 0);
  }

  if (MODE == 1){
    int fl = *flagp;
    #pragma unroll
    for (int i = 0; i < 4; i++){
      int row_l = wr * 64 + i * 16 + quad * 4;
      #pragma unroll
      for (int j = 0; j < 4; j++){
        int col = wc * 64 + j * 16 + lane15;   // N==128, n0==0
        float b = bias[col];
        #pragma unroll
        for (int r = 0; r < 4; r++){
          float v = acc[i][j][r] + b;
          long idx = (m0 + row_l + r) * 128 + col;
          outf[idx] = v;
          ushort_t bb = f2bf(v);
          outb[idx] = bb;
          if (fl) ((ushort_t*)dout)[dout_off + idx] = bb;
          else    ((float*)dout)[dout_off + idx] = v;
        }
      }
    }
  } else if (MODE == 2){
    int fl = *flagp;
    #pragma unroll
    for (int i = 0; i < 4; i++){
      int row_l = wr * 64 + i * 16 + quad * 4;
      #pragma unroll
      for (int j = 0; j < 4; j++){
        int col = n0 + wc * 64 + j * 16 + lane15;
        float b = bias[col];
        #pragma unroll
        for (int r = 0; r < 4; r++){
          float v = acc[i][j][r] + b;
          long idx = (m0 + row_l + r) * N + col;
          if (fl) ((ushort_t*)dout)[dout_off + idx] = f2bf(v);
          else    ((float*)dout)[dout_off + idx] = v;
        }
      }
    }
  } else { // MODE 3
    float bestv[16]; int bestc[16];
    #pragma unroll
    for (int i = 0; i < 4; i++){
      #pragma unroll
      for (int r = 0; r < 4; r++){
        float best = -1e30f; int bcol = 0;
        #pragma unroll
        for (int j = 0; j < 4; j++){
          int col = n0 + wc * 64 + j * 16 + lane15;
          float v = acc[i][j][r] - 0.5f * enorm[col];
          if (v > best){ best = v; bcol = col; }
        }
        #pragma unroll
        for (int off = 1; off < 16; off <<= 1){
          float ov = __shfl_xor(best, off, 64);
          int   oc = __shfl_xor(bcol, off, 64);
          if (ov > best || (ov == best && oc < bcol)){ best = ov; bcol = oc; }
        }
        bestv[i * 4 + r] = best; bestc[i * 4 + r] = bcol;
      }
    }
    __syncthreads();
    float* lv = (float*)As;
    int*   li = (int*)Bs;
    #pragma unroll
    for (int i = 0; i < 4; i++)
      #pragma unroll
      for (int r = 0; r < 4; r++){
        int row_l = wr * 64 + i * 16 + quad * 4 + r;
        if (lane15 == 0){ lv[row_l * 2 + wc] = bestv[i * 4 + r]; li[row_l * 2 + wc] = bestc[i * 4 + r]; }
      }
    __syncthreads();
    if (tid < 128){
      float v0 = lv[tid * 2], v1 = lv[tid * 2 + 1];
      int   c0 = li[tid * 2], c1 = li[tid * 2 + 1];
      float bv; int bc;
      if (v1 > v0 || (v1 == v0 && c1 < c0)){ bv = v1; bc = c1; } else { bv = v0; bc = c0; }
      long row = m0 + tid;
      cand_v[row * 8 + n_idx] = bv;
      cand_i[row * 8 + n_idx] = bc;
    }
  }
}

// =====================================================================
// VQ finalize. grid 16384, block 256 (2 rows / block)
// =====================================================================
__global__ __launch_bounds__(256)
void k_vqfin(const float* __restrict__ cand_v, const int* __restrict__ cand_i,
             const float* __restrict__ zf, const ushort_t* __restrict__ embb,
             ushort_t* __restrict__ qb, void* __restrict__ dout, long zq_off,
             float* __restrict__ loss_part, const int* __restrict__ flagp)
{
  int f = *flagp;
  long row = (long)blockIdx.x * 2 + (threadIdx.x >> 7);
  int d = threadIdx.x & 127;
  float best = -1e30f; int bi = 0;
  #pragma unroll
  for (int nb = 0; nb < 8; nb++){
    float v = cand_v[row * 8 + nb]; int c = cand_i[row * 8 + nb];
    if (v > best || (v == best && c < bi)){ best = v; bi = c; }
  }
  ushort_t qbits = embb[(long)bi * LATENT + d];
  float q = bf2f(qbits);
  long idx = row * LATENT + d;
  qb[idx] = qbits;
  if (f) ((ushort_t*)dout)[zq_off + idx] = qbits;
  else   ((float*)dout)[zq_off + idx] = q;
  float diff = zf[idx] - q;
  float p = diff * diff;
  #pragma unroll
  for (int off = 32; off; off >>= 1) p += __shfl_down(p, off, 64);
  __shared__ float red[4];
  if ((threadIdx.x & 63) == 0) red[threadIdx.x >> 6] = p;
  __syncthreads();
  if (threadIdx.x == 0) loss_part[blockIdx.x] = red[0] + red[1] + red[2] + red[3];
}

__global__ __launch_bounds__(256)
void k_lossfin(const float* __restrict__ loss_part, void* __restrict__ dout,
               long off, const int* __restrict__ flagp){
  __shared__ float red[4];
  float s = 0.f;
  for (int i = threadIdx.x; i < BB / 2; i += 256) s += loss_part[i];
  #pragma unroll
  for (int o = 32; o; o >>= 1) s += __shfl_down(s, o, 64);
  if ((threadIdx.x & 63) == 0) red[threadIdx.x >> 6] = s;
  __syncthreads();
  if (threadIdx.x == 0){
    float v = 1.25f * (red[0] + red[1] + red[2] + red[3]) / (float)((long)BB * LATENT);
    if (*flagp) ((ushort_t*)dout)[off] = f2bf(v);
    else        ((float*)dout)[off] = v;
  }
}

// =====================================================================
extern "C" void kernel_launch(void* const* d_in, const int* in_sizes, int n_in,
                              void* d_out, int out_size, void* d_ws, size_t ws_size,
                              hipStream_t stream)
{
  (void)in_sizes; (void)n_in; (void)out_size; (void)ws_size;
  const void* action = d_in[1];
  const void* eW0 = d_in[2];  const void* eb0 = d_in[3];
  const void* eW1 = d_in[4];  const void* eb1 = d_in[5];
  const void* eW2 = d_in[6];  const void* eb2 = d_in[7];
  const void* emb = d_in[8];
  const void* dW0 = d_in[9];  const void* db0 = d_in[10];
  const void* dW1 = d_in[11]; const void* db1 = d_in[12];
  const void* dW2 = d_in[13]; const void* db2 = d_in[14];

  char* ws = (char*)d_ws;
  size_t off = 0;
  auto alloc = [&](size_t bytes)->char*{
    char* p = ws + off; off += bytes; off = (off + 255) & ~((size_t)255); return p;
  };
  int*      flag     = (int*)  alloc(4);
  float*    biasf    = (float*)alloc(6 * 1024 * 4);
  float*    enorm    = (float*)alloc(KCODES * 4);
  ushort_t* eW0t = (ushort_t*)alloc((size_t)HID * INDIM * 2);
  ushort_t* eW1t = (ushort_t*)alloc((size_t)HID * HID * 2);
  ushort_t* eW2t = (ushort_t*)alloc((size_t)LATENT * HID * 2);
  ushort_t* embb = (ushort_t*)alloc((size_t)KCODES * LATENT * 2);
  ushort_t* dW0t = (ushort_t*)alloc((size_t)HID * LATENT * 2);
  ushort_t* dW1t = (ushort_t*)alloc((size_t)HID * HID * 2);
  ushort_t* dW2t = (ushort_t*)alloc((size_t)INDIM * HID * 2);
  ushort_t* act0 = (ushort_t*)alloc((size_t)BB * INDIM * 2);
  ushort_t* hA   = (ushort_t*)alloc((size_t)BB * HID * 2);
  ushort_t* hB   = (ushort_t*)alloc((size_t)BB * HID * 2);
  float*    zf32 = (float*)   alloc((size_t)BB * LATENT * 4);
  ushort_t* zb16 = (ushort_t*)alloc((size_t)BB * LATENT * 2);
  ushort_t* qb16 = (ushort_t*)alloc((size_t)BB * LATENT * 2);
  float*    cand_v = (float*) alloc((size_t)BB * 8 * 4);
  int*      cand_i = (int*)   alloc((size_t)BB * 8 * 4);
  float*    loss_part = (float*)alloc((size_t)(BB / 2) * 4);

  const long z_off  = (long)BB * INDIM;
  const long zq_off = z_off + (long)BB * LATENT;
  const long l_off  = zq_off + (long)BB * LATENT;

  // ---- prep ----
  k_sniff<<<1, 64, 0, stream>>>((const ushort_t*)action, flag);
  k_cvt<<<(BB * INDIM / 8 + 255) / 256, 256, 0, stream>>>(action, act0, BB * INDIM / 8, flag);
  k_tcvt<<<dim3(HID / 32, INDIM / 32), 256, 0, stream>>>(eW0, eW0t, INDIM, HID, flag);
  k_tcvt<<<dim3(HID / 32, HID / 32),  256, 0, stream>>>(eW1, eW1t, HID, HID, flag);
  k_tcvt<<<dim3(LATENT / 32, HID / 32), 256, 0, stream>>>(eW2, eW2t, HID, LATENT, flag);
  k_tcvt<<<dim3(HID / 32, LATENT / 32), 256, 0, stream>>>(dW0, dW0t, LATENT, HID, flag);
  k_tcvt<<<dim3(HID / 32, HID / 32),  256, 0, stream>>>(dW1, dW1t, HID, HID, flag);
  k_tcvt<<<dim3(INDIM / 32, HID / 32), 256, 0, stream>>>(dW2, dW2t, HID, INDIM, flag);
  k_cvt<<<(KCODES * LATENT / 8 + 255) / 256, 256, 0, stream>>>(emb, embb, KCODES * LATENT / 8, flag);
  k_bias<<<24, 256, 0, stream>>>(eb0, eb1, eb2, db0, db1, db2, biasf, flag);
  k_enorm<<<4, 256, 0, stream>>>(embb, enorm);

  // ---- encoder (wide 128x256 kernel for N=1024 layers) ----
  k_gemmw<<<1024, 256, 0, stream>>>(act0, eW0t, biasf + 0, INDIM, hA);
  k_gemmw<<<1024, 256, 0, stream>>>(hA, eW1t, biasf + 1024, HID, hB);
  k_gemm<1><<<1 * 256, 256, 0, stream>>>(hB, eW2t, biasf + 2048, LATENT, HID,
      zb16, zf32, d_out, z_off, nullptr, nullptr, nullptr, flag);

  // ---- VQ ----
  k_gemm<3><<<8 * 256, 256, 0, stream>>>(zb16, embb, nullptr, KCODES, LATENT,
      nullptr, nullptr, nullptr, 0, enorm, cand_v, cand_i, flag);
  k_vqfin<<<BB / 2, 256, 0, stream>>>(cand_v, cand_i, zf32, embb, qb16, d_out, zq_off,
      loss_part, flag);

  // ---- decoder ----
  k_gemmw<<<1024, 256, 0, stream>>>(qb16, dW0t, biasf + 3072, LATENT, hA);
  k_gemmw<<<1024, 256, 0, stream>>>(hA, dW1t, biasf + 4096, HID, hB);
  k_gemm<2><<<2 * 256, 256, 0, stream>>>(hB, dW2t, biasf + 5120, INDIM, HID,
      nullptr, nullptr, d_out, 0, nullptr, nullptr, nullptr, flag);

  k_lossfin<<<1, 256, 0, stream>>>(loss_part, d_out, l_off, flag);
}

// Round 6
// 479.233 us; speedup vs baseline: 1.8638x; 1.1080x over previous
//
#include <hip/hip_runtime.h>
#include <stdint.h>
#include <math.h>

#define DEVI __device__ __forceinline__
typedef unsigned short ushort_t;
typedef __attribute__((ext_vector_type(8))) __bf16 bf16x8;
typedef __attribute__((ext_vector_type(4))) float f32x4;

// ---------- scalar bf16 helpers (RNE, matches HW/harness encoding) ----------
DEVI float bf2f(ushort_t b){ union{uint32_t u; float f;} c; c.u = ((uint32_t)b) << 16; return c.f; }
DEVI ushort_t f2bf(float f){ union{float f; uint32_t u;} c; c.f = f; uint32_t u = c.u;
                             u += 0x7fffu + ((u >> 16) & 1u); return (ushort_t)(u >> 16); }

// fast tanh: 1 - 2/(exp2(2*log2e*x)+1). ~5 VALU ops, saturates correctly.
DEVI float fast_tanh(float x){
  float t = __builtin_amdgcn_exp2f(x * 2.8853900817779268f);
  return 1.0f - 2.0f * __builtin_amdgcn_rcpf(t + 1.0f);
}

// ---------- async global->LDS (16B per lane, dest = wave-uniform base + lane*16) ----------
DEVI void async16(const ushort_t* g, ushort_t* l){
  __builtin_amdgcn_global_load_lds((const __attribute__((address_space(1))) void*)g,
                                   (__attribute__((address_space(3))) void*)l, 16, 0, 0);
}

// ---------- problem constants ----------
#define BB 32768
#define INDIM 256
#define LATENT 128
#define HID 1024
#define KCODES 1024

// =====================================================================
// dtype sniffer: flag = 1 -> buffers are bf16 ; flag = 0 -> fp32
// =====================================================================
__global__ void k_sniff(const ushort_t* __restrict__ act, int* flag){
  if (threadIdx.x == 0){
    int bad = 0;
    for (int i = 0; i < 256; i++){
      float v = bf2f(act[i]);
      float a = fabsf(v);
      if (!(a <= 16.0f) || (a > 0.0f && a < 9.5e-7f)) bad++;
    }
    flag[0] = (bad >= 8) ? 0 : 1;
  }
}

// convert (no transpose) to bf16 bits, 8 elements / thread (16B stores)
__global__ void k_cvt(const void* __restrict__ src, ushort_t* __restrict__ dst, int n8,
                      const int* __restrict__ flagp){
  int f = *flagp;
  int i = blockIdx.x * blockDim.x + threadIdx.x;
  if (i >= n8) return;
  if (f){
    ((uint4*)dst)[i] = ((const uint4*)src)[i];
  } else {
    const float* s = (const float*)src + (size_t)i * 8;
    ushort_t o[8];
    #pragma unroll
    for (int j = 0; j < 8; j++) o[j] = f2bf(s[j]);
    ((uint4*)dst)[i] = *(const uint4*)o;
  }
}

// all 6 weight transposes in ONE launch (was 6). src[R][C] -> dst[C][R] bf16.
// grid 2816 x 256: seg tile counts 256,1024,128,128,1024,256.
__global__ void k_tcvt6(const void* s0, ushort_t* d0, const void* s1, ushort_t* d1,
                        const void* s2, ushort_t* d2, const void* s3, ushort_t* d3,
                        const void* s4, ushort_t* d4, const void* s5, ushort_t* d5,
                        const int* __restrict__ flagp){
  __shared__ ushort_t tile[32][33];
  int f = *flagp;
  int t = blockIdx.x;
  const void* src; ushort_t* dst; int R, C, lcx;
  if (t < 256)      { src=s0; dst=d0; R=256;  C=1024; lcx=5; }
  else if (t < 1280){ src=s1; dst=d1; R=1024; C=1024; lcx=5; t-=256;  }
  else if (t < 1408){ src=s2; dst=d2; R=1024; C=128;  lcx=2; t-=1280; }
  else if (t < 1536){ src=s3; dst=d3; R=128;  C=1024; lcx=5; t-=1408; }
  else if (t < 2560){ src=s4; dst=d4; R=1024; C=1024; lcx=5; t-=1536; }
  else              { src=s5; dst=d5; R=1024; C=256;  lcx=3; t-=2560; }
  int bx = t & ((C >> 5) - 1), by = t >> lcx;
  int tx = threadIdx.x & 31, ty = threadIdx.x >> 5;
  int c = bx * 32 + tx;
  #pragma unroll
  for (int ii = 0; ii < 4; ii++){
    int r = by * 32 + ty + ii * 8;
    long idx = (long)r * C + c;
    tile[ty + ii * 8][tx] = f ? ((const ushort_t*)src)[idx] : f2bf(((const float*)src)[idx]);
  }
  __syncthreads();
  #pragma unroll
  for (int ii = 0; ii < 4; ii++){
    int cc = bx * 32 + ty + ii * 8;
    dst[(long)cc * R + by * 32 + tx] = tile[tx][ty + ii * 8];
  }
}

// all 6 biases -> fp32, 1024-float slots. grid 24 x 256
__global__ void k_bias(const void* s0, const void* s1, const void* s2,
                       const void* s3, const void* s4, const void* s5,
                       float* __restrict__ d, const int* __restrict__ flagp){
  int f = *flagp;
  int i = blockIdx.x * blockDim.x + threadIdx.x;
  int seg = i >> 10, off = i & 1023;
  const void* sp; int n;
  switch (seg){
    case 0: sp = s0; n = 1024; break;
    case 1: sp = s1; n = 1024; break;
    case 2: sp = s2; n = 128;  break;
    case 3: sp = s3; n = 1024; break;
    case 4: sp = s4; n = 1024; break;
    default: sp = s5; n = 256; break;
  }
  if (off < n)
    d[seg * 1024 + off] = f ? bf2f(((const ushort_t*)sp)[off]) : ((const float*)sp)[off];
}

// ||e_c||^2 from bf16 codebook. grid 4 x 256
__global__ void k_enorm(const ushort_t* __restrict__ embb, float* __restrict__ enorm){
  int c = blockIdx.x * blockDim.x + threadIdx.x;
  if (c < KCODES){
    float s = 0.f;
    for (int d = 0; d < LATENT; d++){ float v = bf2f(embb[c * LATENT + d]); s += v * v; }
    enorm[c] = s;
  }
}

// =====================================================================
// WIDE MFMA GEMM (N==1024): C = tanh(A[M,K] @ Bt[N,K]^T + b)
// 128x256 block tile, BK=64 (R6: halves barriers/vmcnt-drains per MFMA —
// the R5 diagnosis: 228 regs/wave -> 2 blocks/CU, per-iter drain exposed).
// LDS 48 KB (As 16 + Bs 32) -> still 2 blocks/CU at 96 KB.
// Staging rows are 64-k (8 chunks of 8 elem); slot (r,c) holds global
// chunk c^(r&7); reader XORs identically -> 2-way banks (free).
// =====================================================================
__global__ __launch_bounds__(256, 2)
void k_gemmw(const ushort_t* __restrict__ A, const ushort_t* __restrict__ Bt,
             const float* __restrict__ bias, int K,
             ushort_t* __restrict__ outb)
{
  const int N = 1024;
  __shared__ __align__(16) ushort_t As[128 * 64];   // 16 KB
  __shared__ __align__(16) ushort_t Bs[256 * 64];   // 32 KB
  const int tid = threadIdx.x;
  const int w = tid >> 6, lane = tid & 63;
  const int lane15 = lane & 15, quad = lane >> 4;
  const int wr = w >> 1, wc = w & 1;

  // ---- XCD-locality swizzle: 4 n-tiles (256 wide), 256 m-tiles ----
  const int f = blockIdx.x;
  const int j8 = f & 7, s = f >> 3;
  const int n_idx = s & 3;
  const int m_idx = ((s >> 2) << 3) | j8;
  const long m0 = (long)m_idx * 128;
  const int n0 = n_idx * 256;

  // staging lane decomposition: r = lane>>3 (8 rows/shot), c = lane&7
  const int lrow = lane >> 3;
  const int lk8  = (((lane & 7) ^ (lrow & 7)) * 8);   // XOR-swizzled k-chunk
  // fragment-read chunk swizzle source: row ρ -> ρ&7
  const int rx   = lane15 & 7;

  f32x4 acc[4][8];
  #pragma unroll
  for (int i = 0; i < 4; i++)
    #pragma unroll
    for (int j = 0; j < 8; j++) acc[i][j] = (f32x4){0.f, 0.f, 0.f, 0.f};

  const int nk = K >> 6;
  for (int kb = 0; kb < nk; kb++){
    const int k0 = kb << 6;
    __syncthreads();
    #pragma unroll
    for (int a = 0; a < 4; a++){
      int m = w * 32 + a * 8 + lrow;
      async16(A + ((m0 + m) * K + k0 + lk8), &As[(w * 32 + a * 8) * 64]);
    }
    #pragma unroll
    for (int b = 0; b < 8; b++){
      int n = w * 64 + b * 8 + lrow;
      async16(Bt + ((long)(n0 + n) * K + k0 + lk8), &Bs[(w * 64 + b * 8) * 64]);
    }
    __builtin_amdgcn_s_waitcnt(0);
    __syncthreads();

    #pragma unroll
    for (int h = 0; h < 2; h++){
      bf16x8 af[4], bf[8];
      #pragma unroll
      for (int i = 0; i < 4; i++){
        int rho = wr * 64 + i * 16 + lane15;
        af[i] = *(const bf16x8*)&As[rho * 64 + ((((h << 2) | quad) ^ rx) * 8)];
      }
      #pragma unroll
      for (int j = 0; j < 8; j++){
        int rho = wc * 128 + j * 16 + lane15;
        bf[j] = *(const bf16x8*)&Bs[rho * 64 + ((((h << 2) | quad) ^ rx) * 8)];
      }
      #pragma unroll
      for (int i = 0; i < 4; i++)
        #pragma unroll
        for (int j = 0; j < 8; j++)
          acc[i][j] = __builtin_amdgcn_mfma_f32_16x16x32_bf16(af[i], bf[j], acc[i][j], 0, 0, 0);
    }
  }

  #pragma unroll
  for (int i = 0; i < 4; i++){
    int row_l = wr * 64 + i * 16 + quad * 4;
    #pragma unroll
    for (int j = 0; j < 8; j++){
      int col = n0 + wc * 128 + j * 16 + lane15;
      float b = bias[col];
      #pragma unroll
      for (int r = 0; r < 4; r++){
        float v = fast_tanh(acc[i][j][r] + b);
        outb[(m0 + row_l + r) * N + col] = f2bf(v);
      }
    }
  }
}

// =====================================================================
// generic 128x128 MFMA GEMM (z / VQ / dec-L2 shapes). BK=32.
// MODE 1: z: fp32 buf + bf16 buf + d_out (flag dtype)      [N=128]
// MODE 2: recon: d_out only (flag dtype)                   [N=256]
// MODE 3: VQ scores: acc - 0.5*enorm[col], per-row argmax  [N=1024]
// =====================================================================
template<int MODE>
__global__ __launch_bounds__(256)
void k_gemm(const ushort_t* __restrict__ A, const ushort_t* __restrict__ Bt,
            const float* __restrict__ bias, int N, int K,
            ushort_t* __restrict__ outb, float* __restrict__ outf,
            void* __restrict__ dout, long dout_off,
            const float* __restrict__ enorm,
            float* __restrict__ cand_v, int* __restrict__ cand_i,
            const int* __restrict__ flagp)
{
  __shared__ __align__(16) ushort_t As[128 * 32];
  __shared__ __align__(16) ushort_t Bs[128 * 32];
  const int tid = threadIdx.x;
  const int w = tid >> 6, lane = tid & 63;
  const int lane15 = lane & 15, quad = lane >> 4;
  const int wr = w >> 1, wc = w & 1;

  const int nx = N >> 7;
  const int lnx = __builtin_ctz(nx);
  const int f = blockIdx.x;
  const int j8 = f & 7, s = f >> 3;
  const int n_idx = s & (nx - 1);
  const int m_idx = ((s >> lnx) << 3) | j8;
  const long m0 = (long)m_idx * 128;
  const int n0 = n_idx * 128;

  const int lrow = lane >> 2;
  const int lk8  = (((lane & 3) ^ ((lane >> 3) & 3)) * 8);
  const int sw   = (lane15 >> 1) & 3;

  f32x4 acc[4][4];
  #pragma unroll
  for (int i = 0; i < 4; i++)
    #pragma unroll
    for (int j = 0; j < 4; j++) acc[i][j] = (f32x4){0.f, 0.f, 0.f, 0.f};

  const int nk = K >> 5;
  for (int kb = 0; kb < nk; kb++){
    const int k0 = kb << 5;
    __syncthreads();
    #pragma unroll
    for (int ss = 0; ss < 2; ss++){
      int m = w * 32 + ss * 16 + lrow;
      async16(A + ((m0 + m) * K + k0 + lk8), &As[(w * 32 + ss * 16) * 32]);
    }
    #pragma unroll
    for (int ss = 0; ss < 2; ss++){
      int n = w * 32 + ss * 16 + lrow;
      async16(Bt + ((long)(n0 + n) * K + k0 + lk8), &Bs[(w * 32 + ss * 16) * 32]);
    }
    __builtin_amdgcn_s_waitcnt(0);
    __syncthreads();

    bf16x8 af[4], bf[4];
    #pragma unroll
    for (int i = 0; i < 4; i++)
      af[i] = *(const bf16x8*)&As[(wr * 64 + i * 16 + lane15) * 32 + ((quad ^ sw) * 8)];
    #pragma unroll
    for (int j = 0; j < 4; j++)
      bf[j] = *(const bf16x8*)&Bs[(wc * 64 + j * 16 + lane15) * 32 + ((quad ^ sw) * 8)];
    #pragma unroll
    for (int i = 0; i < 4; i++)
      #pragma unroll
      for (int j = 0; j < 4; j++)
        acc[i][j] = __builtin_amdgcn_mfma_f32_16x16x32_bf16(af[i], bf[j], acc[i][j], 0, 0, 0);
  }

  if (MODE == 1){
    int fl = *flagp;
    #pragma unroll
    for (int i = 0; i < 4; i++){
      int row_l = wr * 64 + i * 16 + quad * 4;
      #pragma unroll
      for (int j = 0; j < 4; j++){
        int col = wc * 64 + j * 16 + lane15;   // N==128, n0==0
        float b = bias[col];
        #pragma unroll
        for (int r = 0; r < 4; r++){
          float v = acc[i][j][r] + b;
          long idx = (m0 + row_l + r) * 128 + col;
          outf[idx] = v;
          ushort_t bb = f2bf(v);
          outb[idx] = bb;
          if (fl) ((ushort_t*)dout)[dout_off + idx] = bb;
          else    ((float*)dout)[dout_off + idx] = v;
        }
      }
    }
  } else if (MODE == 2){
    int fl = *flagp;
    #pragma unroll
    for (int i = 0; i < 4; i++){
      int row_l = wr * 64 + i * 16 + quad * 4;
      #pragma unroll
      for (int j = 0; j < 4; j++){
        int col = n0 + wc * 64 + j * 16 + lane15;
        float b = bias[col];
        #pragma unroll
        for (int r = 0; r < 4; r++){
          float v = acc[i][j][r] + b;
          long idx = (m0 + row_l + r) * N + col;
          if (fl) ((ushort_t*)dout)[dout_off + idx] = f2bf(v);
          else    ((float*)dout)[dout_off + idx] = v;
        }
      }
    }
  } else { // MODE 3
    float bestv[16]; int bestc[16];
    #pragma unroll
    for (int i = 0; i < 4; i++){
      #pragma unroll
      for (int r = 0; r < 4; r++){
        float best = -1e30f; int bcol = 0;
        #pragma unroll
        for (int j = 0; j < 4; j++){
          int col = n0 + wc * 64 + j * 16 + lane15;
          float v = acc[i][j][r] - 0.5f * enorm[col];
          if (v > best){ best = v; bcol = col; }
        }
        #pragma unroll
        for (int off = 1; off < 16; off <<= 1){
          float ov = __shfl_xor(best, off, 64);
          int   oc = __shfl_xor(bcol, off, 64);
          if (ov > best || (ov == best && oc < bcol)){ best = ov; bcol = oc; }
        }
        bestv[i * 4 + r] = best; bestc[i * 4 + r] = bcol;
      }
    }
    __syncthreads();
    float* lv = (float*)As;
    int*   li = (int*)Bs;
    #pragma unroll
    for (int i = 0; i < 4; i++)
      #pragma unroll
      for (int r = 0; r < 4; r++){
        int row_l = wr * 64 + i * 16 + quad * 4 + r;
        if (lane15 == 0){ lv[row_l * 2 + wc] = bestv[i * 4 + r]; li[row_l * 2 + wc] = bestc[i * 4 + r]; }
      }
    __syncthreads();
    if (tid < 128){
      float v0 = lv[tid * 2], v1 = lv[tid * 2 + 1];
      int   c0 = li[tid * 2], c1 = li[tid * 2 + 1];
      float bv; int bc;
      if (v1 > v0 || (v1 == v0 && c1 < c0)){ bv = v1; bc = c1; } else { bv = v0; bc = c0; }
      long row = m0 + tid;
      cand_v[row * 8 + n_idx] = bv;
      cand_i[row * 8 + n_idx] = bc;
    }
  }
}

// =====================================================================
// VQ finalize. grid 16384, block 256 (2 rows / block)
// =====================================================================
__global__ __launch_bounds__(256)
void k_vqfin(const float* __restrict__ cand_v, const int* __restrict__ cand_i,
             const float* __restrict__ zf, const ushort_t* __restrict__ embb,
             ushort_t* __restrict__ qb, void* __restrict__ dout, long zq_off,
             float* __restrict__ loss_part, const int* __restrict__ flagp)
{
  int f = *flagp;
  long row = (long)blockIdx.x * 2 + (threadIdx.x >> 7);
  int d = threadIdx.x & 127;
  float best = -1e30f; int bi = 0;
  #pragma unroll
  for (int nb = 0; nb < 8; nb++){
    float v = cand_v[row * 8 + nb]; int c = cand_i[row * 8 + nb];
    if (v > best || (v == best && c < bi)){ best = v; bi = c; }
  }
  ushort_t qbits = embb[(long)bi * LATENT + d];
  float q = bf2f(qbits);
  long idx = row * LATENT + d;
  qb[idx] = qbits;
  if (f) ((ushort_t*)dout)[zq_off + idx] = qbits;
  else   ((float*)dout)[zq_off + idx] = q;
  float diff = zf[idx] - q;
  float p = diff * diff;
  #pragma unroll
  for (int off = 32; off; off >>= 1) p += __shfl_down(p, off, 64);
  __shared__ float red[4];
  if ((threadIdx.x & 63) == 0) red[threadIdx.x >> 6] = p;
  __syncthreads();
  if (threadIdx.x == 0) loss_part[blockIdx.x] = red[0] + red[1] + red[2] + red[3];
}

__global__ __launch_bounds__(256)
void k_lossfin(const float* __restrict__ loss_part, void* __restrict__ dout,
               long off, const int* __restrict__ flagp){
  __shared__ float red[4];
  float s = 0.f;
  for (int i = threadIdx.x; i < BB / 2; i += 256) s += loss_part[i];
  #pragma unroll
  for (int o = 32; o; o >>= 1) s += __shfl_down(s, o, 64);
  if ((threadIdx.x & 63) == 0) red[threadIdx.x >> 6] = s;
  __syncthreads();
  if (threadIdx.x == 0){
    float v = 1.25f * (red[0] + red[1] + red[2] + red[3]) / (float)((long)BB * LATENT);
    if (*flagp) ((ushort_t*)dout)[off] = f2bf(v);
    else        ((float*)dout)[off] = v;
  }
}

// =====================================================================
extern "C" void kernel_launch(void* const* d_in, const int* in_sizes, int n_in,
                              void* d_out, int out_size, void* d_ws, size_t ws_size,
                              hipStream_t stream)
{
  (void)in_sizes; (void)n_in; (void)out_size; (void)ws_size;
  const void* action = d_in[1];
  const void* eW0 = d_in[2];  const void* eb0 = d_in[3];
  const void* eW1 = d_in[4];  const void* eb1 = d_in[5];
  const void* eW2 = d_in[6];  const void* eb2 = d_in[7];
  const void* emb = d_in[8];
  const void* dW0 = d_in[9];  const void* db0 = d_in[10];
  const void* dW1 = d_in[11]; const void* db1 = d_in[12];
  const void* dW2 = d_in[13]; const void* db2 = d_in[14];

  char* ws = (char*)d_ws;
  size_t off = 0;
  auto alloc = [&](size_t bytes)->char*{
    char* p = ws + off; off += bytes; off = (off + 255) & ~((size_t)255); return p;
  };
  int*      flag     = (int*)  alloc(4);
  float*    biasf    = (float*)alloc(6 * 1024 * 4);
  float*    enorm    = (float*)alloc(KCODES * 4);
  ushort_t* eW0t = (ushort_t*)alloc((size_t)HID * INDIM * 2);
  ushort_t* eW1t = (ushort_t*)alloc((size_t)HID * HID * 2);
  ushort_t* eW2t = (ushort_t*)alloc((size_t)LATENT * HID * 2);
  ushort_t* embb = (ushort_t*)alloc((size_t)KCODES * LATENT * 2);
  ushort_t* dW0t = (ushort_t*)alloc((size_t)HID * LATENT * 2);
  ushort_t* dW1t = (ushort_t*)alloc((size_t)HID * HID * 2);
  ushort_t* dW2t = (ushort_t*)alloc((size_t)INDIM * HID * 2);
  ushort_t* act0 = (ushort_t*)alloc((size_t)BB * INDIM * 2);
  ushort_t* hA   = (ushort_t*)alloc((size_t)BB * HID * 2);
  ushort_t* hB   = (ushort_t*)alloc((size_t)BB * HID * 2);
  float*    zf32 = (float*)   alloc((size_t)BB * LATENT * 4);
  ushort_t* zb16 = (ushort_t*)alloc((size_t)BB * LATENT * 2);
  ushort_t* qb16 = (ushort_t*)alloc((size_t)BB * LATENT * 2);
  float*    cand_v = (float*) alloc((size_t)BB * 8 * 4);
  int*      cand_i = (int*)   alloc((size_t)BB * 8 * 4);
  float*    loss_part = (float*)alloc((size_t)(BB / 2) * 4);

  const long z_off  = (long)BB * INDIM;
  const long zq_off = z_off + (long)BB * LATENT;
  const long l_off  = zq_off + (long)BB * LATENT;

  // ---- prep ----
  k_sniff<<<1, 64, 0, stream>>>((const ushort_t*)action, flag);
  k_cvt<<<(BB * INDIM / 8 + 255) / 256, 256, 0, stream>>>(action, act0, BB * INDIM / 8, flag);
  k_tcvt6<<<2816, 256, 0, stream>>>(eW0, eW0t, eW1, eW1t, eW2, eW2t,
                                    dW0, dW0t, dW1, dW1t, dW2, dW2t, flag);
  k_cvt<<<(KCODES * LATENT / 8 + 255) / 256, 256, 0, stream>>>(emb, embb, KCODES * LATENT / 8, flag);
  k_bias<<<24, 256, 0, stream>>>(eb0, eb1, eb2, db0, db1, db2, biasf, flag);
  k_enorm<<<4, 256, 0, stream>>>(embb, enorm);

  // ---- encoder (wide 128x256/BK=64 kernel for N=1024 layers) ----
  k_gemmw<<<1024, 256, 0, stream>>>(act0, eW0t, biasf + 0, INDIM, hA);
  k_gemmw<<<1024, 256, 0, stream>>>(hA, eW1t, biasf + 1024, HID, hB);
  k_gemm<1><<<1 * 256, 256, 0, stream>>>(hB, eW2t, biasf + 2048, LATENT, HID,
      zb16, zf32, d_out, z_off, nullptr, nullptr, nullptr, flag);

  // ---- VQ ----
  k_gemm<3><<<8 * 256, 256, 0, stream>>>(zb16, embb, nullptr, KCODES, LATENT,
      nullptr, nullptr, nullptr, 0, enorm, cand_v, cand_i, flag);
  k_vqfin<<<BB / 2, 256, 0, stream>>>(cand_v, cand_i, zf32, embb, qb16, d_out, zq_off,
      loss_part, flag);

  // ---- decoder ----
  k_gemmw<<<1024, 256, 0, stream>>>(qb16, dW0t, biasf + 3072, LATENT, hA);
  k_gemmw<<<1024, 256, 0, stream>>>(hA, dW1t, biasf + 4096, HID, hB);
  k_gemm<2><<<2 * 256, 256, 0, stream>>>(hB, dW2t, biasf + 5120, INDIM, HID,
      nullptr, nullptr, d_out, 0, nullptr, nullptr, nullptr, flag);

  k_lossfin<<<1, 256, 0, stream>>>(loss_part, d_out, l_off, flag);
}